// Round 1
// 510.103 us; speedup vs baseline: 1.0131x; 1.0131x over previous
//
#include <hip/hip_runtime.h>

#define D 1024
#define HD 128
#define EA 8
#define EF 16
#define FH 512
#define MAXPOS 64
#define RNUM 129
#define RSTRIDE 132
#define SEQ 1024
#define NTOK 4096
#define NPAIR (NTOK * 2)
#define NPAD 8320          // NPAIR + 128 slack
#define LN_EPS 1e-5f
#define QSCALE 0.08838834764831845f
#define BSTR 32            // linear LDS row stride in bf16 elems (global_load_lds needs linear)
#define PROW 2048          // bf16 P row stride in ushorts (= SEQ*4B slot)

typedef __attribute__((ext_vector_type(8))) short bf16x8;
typedef __attribute__((ext_vector_type(4))) float f32x4;
typedef __attribute__((ext_vector_type(8))) unsigned short u16x8;

__device__ inline ushort f2b(float f) {
    union { float f; unsigned u; } v; v.f = f;
    unsigned r = (v.u + 0x7fffu + ((v.u >> 16) & 1u)) >> 16;
    return (ushort)r;
}
__device__ inline float b2f(ushort u) {
    union { unsigned u; float f; } v; v.u = (unsigned)u << 16; return v.f;
}

// async global->LDS, 16B per lane, dest = wave-uniform base + lane*16
__device__ __forceinline__ void gll(const void* g, void* l) {
    __builtin_amdgcn_global_load_lds((const __attribute__((address_space(1))) void*)g,
                                     (__attribute__((address_space(3))) void*)l, 16, 0, 0);
}

// one double-buffer compute step: 64x128 tile, wave = 32x64
__device__ inline void mfma_step(const short* Asb, const short* Bsb,
                                 int wr, int wc, int m16, int q, f32x4 (&acc)[2][4]) {
    bf16x8 af[2], bfr[4];
#pragma unroll
    for (int i = 0; i < 2; i++) af[i] = *(const bf16x8*)&Asb[(wr + i * 16 + m16) * BSTR + q * 8];
#pragma unroll
    for (int j = 0; j < 4; j++) bfr[j] = *(const bf16x8*)&Bsb[(wc + j * 16 + m16) * BSTR + q * 8];
#pragma unroll
    for (int i = 0; i < 2; i++)
#pragma unroll
        for (int j = 0; j < 4; j++)
            acc[i][j] = __builtin_amdgcn_mfma_f32_16x16x32_bf16(af[i], bfr[j], acc[i][j], 0, 0, 0);
}

// ---------------- LayerNorm (fp32 out for router + bf16 out for GEMMs) ----------------
__global__ void ln_kernel(const float* __restrict__ x, const float* __restrict__ w,
                          const float* __restrict__ b, float* __restrict__ y,
                          ushort* __restrict__ yb) {
    int row = blockIdx.x;
    const float* xr = x + (size_t)row * D;
    float v[4];
    float s = 0.f, s2 = 0.f;
#pragma unroll
    for (int i = 0; i < 4; i++) {
        v[i] = xr[threadIdx.x + i * 256];
        s += v[i]; s2 += v[i] * v[i];
    }
#pragma unroll
    for (int off = 32; off; off >>= 1) { s += __shfl_down(s, off); s2 += __shfl_down(s2, off); }
    __shared__ float red0[4], red1[4];
    int wave = threadIdx.x >> 6, lane = threadIdx.x & 63;
    if (lane == 0) { red0[wave] = s; red1[wave] = s2; }
    __syncthreads();
    float ts = red0[0] + red0[1] + red0[2] + red0[3];
    float ts2 = red1[0] + red1[1] + red1[2] + red1[3];
    float mu = ts * (1.f / D);
    float var = ts2 * (1.f / D) - mu * mu;
    float inv = rsqrtf(var + LN_EPS);
#pragma unroll
    for (int i = 0; i < 4; i++) {
        int d = threadIdx.x + i * 256;
        float o = (v[i] - mu) * inv * w[d] + b[d];
        y[(size_t)row * D + d] = o;
        yb[(size_t)row * D + d] = f2b(o);
    }
}

// ---------------- Router ----------------
template <int E>
__global__ void router_kernel(const float* __restrict__ xn, const float* __restrict__ gw,
                              int* __restrict__ idx, float* __restrict__ gate) {
    int t = blockIdx.x;
    int lane = threadIdx.x;  // block=64
    float acc[E];
#pragma unroll
    for (int e = 0; e < E; e++) acc[e] = 0.f;
    const float* xr = xn + (size_t)t * D;
    for (int d = lane; d < D; d += 64) {
        float xv = xr[d];
#pragma unroll
        for (int e = 0; e < E; e++) acc[e] += xv * gw[d * E + e];
    }
#pragma unroll
    for (int e = 0; e < E; e++) {
#pragma unroll
        for (int off = 32; off; off >>= 1) acc[e] += __shfl_down(acc[e], off);
    }
    if (lane == 0) {
        float v0 = -1e30f, v1 = -1e30f;
        int i0 = 0, i1 = 0;
#pragma unroll
        for (int e = 0; e < E; e++) {
            float a = acc[e];
            if (a > v0) { v1 = v0; i1 = i0; v0 = a; i0 = e; }
            else if (a > v1) { v1 = a; i1 = e; }
        }
        float g0 = 1.f / (1.f + expf(v1 - v0));
        idx[t * 2] = i0; idx[t * 2 + 1] = i1;
        gate[t * 2] = g0; gate[t * 2 + 1] = 1.f - g0;
    }
}

// ---------------- Attention binning: 32 bins keyed (expert*4 + batch) ----------------
__global__ void abin_zero(int* __restrict__ meta) {
    if (threadIdx.x < 105) meta[threadIdx.x] = 0;
}
__global__ void abin_count(const int* __restrict__ aidx, int* __restrict__ meta) {
    int i = blockIdx.x * 256 + threadIdx.x;
    if (i < NPAIR) {
        int e = aidx[i];
        int b = (i >> 1) >> 10;
        atomicAdd(&meta[e * 4 + b], 1);
    }
}
__global__ void abin_scan(int* __restrict__ meta) {
    if (threadIdx.x == 0 && blockIdx.x == 0) {
        int s = 0;
        for (int bin = 0; bin < 32; bin++) {
            if ((bin & 3) == 0) meta[96 + (bin >> 2)] = s;
            meta[32 + bin] = s; meta[64 + bin] = s; s += meta[bin];
        }
        meta[96 + 8] = s;
    }
}
__global__ void abin_scatter(const int* __restrict__ aidx, int* __restrict__ meta,
                             int* __restrict__ list, int* __restrict__ inv) {
    int i = blockIdx.x * 256 + threadIdx.x;
    if (i < NPAIR) {
        int e = aidx[i];
        int b = (i >> 1) >> 10;
        int pos = atomicAdd(&meta[64 + e * 4 + b], 1);
        list[pos] = i;
        inv[i] = pos;
    }
}

// ---------------- FFN binning ----------------
__global__ void bin_zero(int* __restrict__ meta) {
    if (threadIdx.x < 48) meta[threadIdx.x] = 0;
}
__global__ void bin_count(const int* __restrict__ fidx, int* __restrict__ meta) {
    int i = blockIdx.x * 256 + threadIdx.x;
    if (i < NPAIR) atomicAdd(&meta[fidx[i]], 1);
}
__global__ void bin_scan(int* __restrict__ meta) {
    if (threadIdx.x == 0 && blockIdx.x == 0) {
        int s = 0;
        for (int e = 0; e < EF; e++) { meta[16 + e] = s; meta[32 + e] = s; s += meta[e]; }
    }
}
__global__ void bin_scatter(const int* __restrict__ fidx, int* __restrict__ meta,
                            int* __restrict__ list, int* __restrict__ inv) {
    int i = blockIdx.x * 256 + threadIdx.x;
    if (i < NPAIR) {
        int e = fidx[i];
        int pos = atomicAdd(&meta[32 + e], 1);
        list[pos] = i;
        inv[i] = pos;
    }
}

// ---------------- transpose-convert [E][R][C] fp32 -> [E][C][R] bf16 ----------------
template <int R, int C>
__global__ void convT_kernel(const float* __restrict__ in, ushort* __restrict__ out) {
    int e = blockIdx.z;
    int r0 = blockIdx.x * 32, c0 = blockIdx.y * 32;
    __shared__ float tile[32][33];
    int tx = threadIdx.x & 31, ty = threadIdx.x >> 5;  // 256 thr
    const float* src = in + (size_t)e * R * C;
#pragma unroll
    for (int i = 0; i < 32; i += 8)
        tile[ty + i][tx] = src[(size_t)(r0 + ty + i) * C + c0 + tx];
    __syncthreads();
    ushort* dst = out + (size_t)e * C * R;
#pragma unroll
    for (int i = 0; i < 32; i += 8)
        dst[(size_t)(c0 + ty + i) * R + r0 + tx] = f2b(tile[tx][ty + i]);
}

// elementwise fp32 -> bf16 (small arrays)
__global__ void conv_kernel(const float* __restrict__ in, ushort* __restrict__ out, int n) {
    int i = blockIdx.x * 256 + threadIdx.x;
    if (i < n) out[i] = f2b(in[i]);
}

// ---- staging geometry (shared by all GEMMs):
//   wave w stages A rows [w*16, w*16+16) and B rows [w*32, w*32+32) of the tile,
//   one 1KB global_load_lds issue covers 16 rows x 64B; lane l -> row l>>2, byte (l&3)*16.

// ---------------- kv: split-K MFMA, dense per-split partials ----------------
__global__ __launch_bounds__(256) void kv_mfma(
    const ushort* __restrict__ xnb, const ushort* __restrict__ kwt,
    const ushort* __restrict__ vwt, float* __restrict__ kpart, float* __restrict__ vpart) {
    const ushort* W = blockIdx.z ? vwt : kwt;
    float* outp = blockIdx.z ? vpart : kpart;
    int m0 = blockIdx.x * 64;
    int s = blockIdx.y;
    int kbase = s * 256;
    __shared__ __align__(16) short As[2][64 * BSTR];
    __shared__ __align__(16) short Bs[2][128 * BSTR];
    int tid = threadIdx.x, w = tid >> 6, lane = tid & 63;
    int sr = lane >> 2, sc = (lane & 3) * 8;
    const ushort* ap = xnb + (size_t)(m0 + w * 16 + sr) * D + kbase + sc;
    const ushort* bp0 = W + (size_t)(w * 32 + sr) * D + kbase + sc;
    const ushort* bp1 = bp0 + (size_t)16 * D;
    int wr = (w >> 1) * 32, wc = (w & 1) * 64;
    int m16 = lane & 15, q = lane >> 4;
    f32x4 acc[2][4] = {};
    gll(ap, &As[0][w * 512]); gll(bp0, &Bs[0][w * 1024]); gll(bp1, &Bs[0][w * 1024 + 512]);
    __syncthreads();
    int cur = 0;
    for (int k = 1; k < 8; k++) {
        int nxt = cur ^ 1;
        gll(ap + k * 32, &As[nxt][w * 512]);
        gll(bp0 + k * 32, &Bs[nxt][w * 1024]);
        gll(bp1 + k * 32, &Bs[nxt][w * 1024 + 512]);
        mfma_step(As[cur], Bs[cur], wr, wc, m16, q, acc);
        __syncthreads();
        cur = nxt;
    }
    mfma_step(As[cur], Bs[cur], wr, wc, m16, q, acc);
#pragma unroll
    for (int i = 0; i < 2; i++)
#pragma unroll
        for (int r = 0; r < 4; r++) {
            int m = m0 + wr + i * 16 + q * 4 + r;
#pragma unroll
            for (int j = 0; j < 4; j++)
                outp[((size_t)s * NTOK + m) * HD + wc + j * 16 + m16] = acc[i][j][r];
        }
}

__global__ void kv_reduce(const float* __restrict__ kpart, const float* __restrict__ vpart,
                          const float* __restrict__ kb, const float* __restrict__ vb,
                          ushort* __restrict__ kb16, float* __restrict__ vbf) {
    int t = blockIdx.x, h = threadIdx.x;  // 128
    float ka = kb[h], va = vb[h];
#pragma unroll
    for (int s = 0; s < 4; s++) {
        ka += kpart[((size_t)s * NTOK + t) * HD + h];
        va += vpart[((size_t)s * NTOK + t) * HD + h];
    }
    kb16[(size_t)t * HD + h] = f2b(ka);
    vbf[(size_t)t * HD + h] = va;
}

// ---------------- q: split-K MFMA, indirect A, dense partials ----------------
__global__ __launch_bounds__(256) void q_mfma(
    const ushort* __restrict__ xnb, const ushort* __restrict__ qwt,
    const int* __restrict__ meta, const int* __restrict__ list, float* __restrict__ qpart) {
    int e = blockIdx.z;
    int o = meta[96 + e], c = meta[97 + e] - o;
    int m0 = blockIdx.x * 64;
    if (m0 >= c) return;
    int s = blockIdx.y;
    int kbase = s * 256;
    __shared__ __align__(16) short As[2][64 * BSTR];
    __shared__ __align__(16) short Bs[2][128 * BSTR];
    int tid = threadIdx.x, w = tid >> 6, lane = tid & 63;
    int sr = lane >> 2, sc = (lane & 3) * 8;
    int ri = o + m0 + w * 16 + sr; if (ri > NPAIR - 1) ri = NPAIR - 1;
    const ushort* ap = xnb + (size_t)(list[ri] >> 1) * D + kbase + sc;
    const ushort* bp0 = qwt + (size_t)e * HD * D + (size_t)(w * 32 + sr) * D + kbase + sc;
    const ushort* bp1 = bp0 + (size_t)16 * D;
    int wr = (w >> 1) * 32, wc = (w & 1) * 64;
    int m16 = lane & 15, q = lane >> 4;
    f32x4 acc[2][4] = {};
    gll(ap, &As[0][w * 512]); gll(bp0, &Bs[0][w * 1024]); gll(bp1, &Bs[0][w * 1024 + 512]);
    __syncthreads();
    int cur = 0;
    for (int k = 1; k < 8; k++) {
        int nxt = cur ^ 1;
        gll(ap + k * 32, &As[nxt][w * 512]);
        gll(bp0 + k * 32, &Bs[nxt][w * 1024]);
        gll(bp1 + k * 32, &Bs[nxt][w * 1024 + 512]);
        mfma_step(As[cur], Bs[cur], wr, wc, m16, q, acc);
        __syncthreads();
        cur = nxt;
    }
    mfma_step(As[cur], Bs[cur], wr, wc, m16, q, acc);
#pragma unroll
    for (int i = 0; i < 2; i++)
#pragma unroll
        for (int r = 0; r < 4; r++) {
            int pos = o + m0 + wr + i * 16 + q * 4 + r;
            if (pos < o + c) {
#pragma unroll
                for (int j = 0; j < 4; j++)
                    qpart[((size_t)s * NPAD + pos) * HD + wc + j * 16 + m16] = acc[i][j][r];
            }
        }
}

__global__ void q_reduce(const float* __restrict__ qpart, const float* __restrict__ qb,
                         const int* __restrict__ aidx, const int* __restrict__ list,
                         ushort* __restrict__ Qg) {
    int pos = blockIdx.x, h = threadIdx.x;  // 128
    int e = aidx[list[pos]];
    float a = qb[e * HD + h];
#pragma unroll
    for (int s = 0; s < 4; s++) a += qpart[((size_t)s * NPAD + pos) * HD + h];
    Qg[(size_t)pos * HD + h] = f2b(a * QSCALE);
}

// ---------------- rel: MFMA GEMM  R[pos][r] = Qg[pos] . rel[r] ----------------
__global__ __launch_bounds__(256) void rel_mfma(
    const ushort* __restrict__ Qg, const ushort* __restrict__ relb,
    float* __restrict__ R) {
    int m0 = blockIdx.x * 64;
    int n0 = blockIdx.y * 128;
    __shared__ __align__(16) short As[2][64 * BSTR];
    __shared__ __align__(16) short Bs[2][128 * BSTR];
    int tid = threadIdx.x, w = tid >> 6, lane = tid & 63;
    int sr = lane >> 2, sc = (lane & 3) * 8;
    const ushort* ap = Qg + (size_t)(m0 + w * 16 + sr) * HD + sc;
    int r0 = n0 + w * 32 + sr;      if (r0 > RNUM - 1) r0 = RNUM - 1;
    int r1 = n0 + w * 32 + 16 + sr; if (r1 > RNUM - 1) r1 = RNUM - 1;
    const ushort* bp0 = relb + (size_t)r0 * HD + sc;
    const ushort* bp1 = relb + (size_t)r1 * HD + sc;
    int wr = (w >> 1) * 32, wc = (w & 1) * 64;
    int m16 = lane & 15, q = lane >> 4;
    f32x4 acc[2][4] = {};
    gll(ap, &As[0][w * 512]); gll(bp0, &Bs[0][w * 1024]); gll(bp1, &Bs[0][w * 1024 + 512]);
    __syncthreads();
    int cur = 0;
    for (int k = 1; k < 4; k++) {
        int nxt = cur ^ 1;
        gll(ap + k * 32, &As[nxt][w * 512]);
        gll(bp0 + k * 32, &Bs[nxt][w * 1024]);
        gll(bp1 + k * 32, &Bs[nxt][w * 1024 + 512]);
        mfma_step(As[cur], Bs[cur], wr, wc, m16, q, acc);
        __syncthreads();
        cur = nxt;
    }
    mfma_step(As[cur], Bs[cur], wr, wc, m16, q, acc);
#pragma unroll
    for (int i = 0; i < 2; i++)
#pragma unroll
        for (int r = 0; r < 4; r++) {
            int pos = m0 + wr + i * 16 + q * 4 + r;
#pragma unroll
            for (int j = 0; j < 4; j++) {
                int n = n0 + wc + j * 16 + m16;
                if (n < RNUM) R[(size_t)pos * RSTRIDE + n] = acc[i][j][r];
            }
        }
}

// ---------------- s: MFMA QK^T + rel bias, fp32 S out ----------------
__global__ __launch_bounds__(256) void s_mfma(
    const ushort* __restrict__ Qg, const ushort* __restrict__ kb16,
    const float* __restrict__ R, const int* __restrict__ meta,
    const int* __restrict__ list, float* __restrict__ S) {
    int bin = blockIdx.z;
    int o = meta[32 + bin], c = meta[bin];
    int m0 = blockIdx.x * 64;
    if (m0 >= c) return;
    int b = bin & 3;
    int n0 = blockIdx.y * 128;
    __shared__ __align__(16) short As[2][64 * BSTR];
    __shared__ __align__(16) short Bs[2][128 * BSTR];
    int tid = threadIdx.x, w = tid >> 6, lane = tid & 63;
    int sr = lane >> 2, sc = (lane & 3) * 8;
    const ushort* ap = Qg + (size_t)(o + m0 + w * 16 + sr) * HD + sc;
    const ushort* bp0 = kb16 + (size_t)b * SEQ * HD + (size_t)(n0 + w * 32 + sr) * HD + sc;
    const ushort* bp1 = bp0 + (size_t)16 * HD;
    int wr = (w >> 1) * 32, wc = (w & 1) * 64;
    int m16 = lane & 15, q = lane >> 4;
    f32x4 acc[2][4] = {};
    gll(ap, &As[0][w * 512]); gll(bp0, &Bs[0][w * 1024]); gll(bp1, &Bs[0][w * 1024 + 512]);
    __syncthreads();
    int cur = 0;
    for (int k = 1; k < 4; k++) {
        int nxt = cur ^ 1;
        gll(ap + k * 32, &As[nxt][w * 512]);
        gll(bp0 + k * 32, &Bs[nxt][w * 1024]);
        gll(bp1 + k * 32, &Bs[nxt][w * 1024 + 512]);
        mfma_step(As[cur], Bs[cur], wr, wc, m16, q, acc);
        __syncthreads();
        cur = nxt;
    }
    mfma_step(As[cur], Bs[cur], wr, wc, m16, q, acc);
#pragma unroll
    for (int i = 0; i < 2; i++)
#pragma unroll
        for (int r = 0; r < 4; r++) {
            int pos = o + m0 + wr + i * 16 + q * 4 + r;
            if (pos < o + c) {
                int qpos = (list[pos] >> 1) & (SEQ - 1);
                const float* Rrow = R + (size_t)pos * RSTRIDE;
                float* sr_ = S + (size_t)pos * SEQ;
#pragma unroll
                for (int j = 0; j < 4; j++) {
                    int key = n0 + wc + j * 16 + m16;
                    int rix = key - qpos;
                    rix = (rix < -MAXPOS ? -MAXPOS : (rix > MAXPOS ? MAXPOS : rix)) + MAXPOS;
                    sr_[key] = acc[i][j][r] + Rrow[rix];
                }
            }
        }
}

// ---------------- Row softmax: fp32 S in, bf16 P out (in place, same row slot) ----------------
__global__ __launch_bounds__(256) void softmax_kernel(float* __restrict__ S) {
    int row = blockIdx.x;
    float4* sr = (float4*)(S + (size_t)row * SEQ);
    float4 v = sr[threadIdx.x];
    float m = fmaxf(fmaxf(v.x, v.y), fmaxf(v.z, v.w));
#pragma unroll
    for (int off = 32; off; off >>= 1) m = fmaxf(m, __shfl_down(m, off));
    __shared__ float red0[4], red1[4];
    int wave = threadIdx.x >> 6, lane = threadIdx.x & 63;
    if (lane == 0) red0[wave] = m;
    __syncthreads();
    m = fmaxf(fmaxf(red0[0], red0[1]), fmaxf(red0[2], red0[3]));
    v.x = __expf(v.x - m); v.y = __expf(v.y - m);
    v.z = __expf(v.z - m); v.w = __expf(v.w - m);
    float s = v.x + v.y + v.z + v.w;
#pragma unroll
    for (int off = 32; off; off >>= 1) s += __shfl_down(s, off);
    if (lane == 0) red1[wave] = s;
    __syncthreads();
    float inv = 1.f / (red1[0] + red1[1] + red1[2] + red1[3]);
    // all reads of this row completed before the preceding barrier; safe in-place bf16 write
    ushort* pr = (ushort*)(S + (size_t)row * SEQ);
    ushort4 p4 = { f2b(v.x * inv), f2b(v.y * inv), f2b(v.z * inv), f2b(v.w * inv) };
    *(ushort4*)(pr + threadIdx.x * 4) = p4;
}

// ---------------- pv: split-K MFMA P@V (bf16 P direct), dense partials ----------------
__global__ __launch_bounds__(256) void pv_mfma(
    const ushort* __restrict__ Pb, const ushort* __restrict__ vt16,
    const int* __restrict__ meta, float* __restrict__ ppart) {
    int bin = blockIdx.z;
    int o = meta[32 + bin], c = meta[bin];
    int m0 = blockIdx.x * 64;
    if (m0 >= c) return;
    int b = bin & 3;
    int s = blockIdx.y;
    int kbase = s * 256;
    __shared__ __align__(16) short As[2][64 * BSTR];
    __shared__ __align__(16) short Bs[2][128 * BSTR];
    int tid = threadIdx.x, w = tid >> 6, lane = tid & 63;
    int sr = lane >> 2, sc = (lane & 3) * 8;
    const ushort* ap = Pb + (size_t)(o + m0 + w * 16 + sr) * PROW + kbase + sc;
    const ushort* bp0 = vt16 + (size_t)b * HD * SEQ + (size_t)(w * 32 + sr) * SEQ + kbase + sc;
    const ushort* bp1 = bp0 + (size_t)16 * SEQ;
    int wr = (w >> 1) * 32, wc = (w & 1) * 64;
    int m16 = lane & 15, q = lane >> 4;
    f32x4 acc[2][4] = {};
    gll(ap, &As[0][w * 512]); gll(bp0, &Bs[0][w * 1024]); gll(bp1, &Bs[0][w * 1024 + 512]);
    __syncthreads();
    int cur = 0;
    for (int k = 1; k < 8; k++) {
        int nxt = cur ^ 1;
        gll(ap + k * 32, &As[nxt][w * 512]);
        gll(bp0 + k * 32, &Bs[nxt][w * 1024]);
        gll(bp1 + k * 32, &Bs[nxt][w * 1024 + 512]);
        mfma_step(As[cur], Bs[cur], wr, wc, m16, q, acc);
        __syncthreads();
        cur = nxt;
    }
    mfma_step(As[cur], Bs[cur], wr, wc, m16, q, acc);
#pragma unroll
    for (int i = 0; i < 2; i++)
#pragma unroll
        for (int r = 0; r < 4; r++) {
            int pos = o + m0 + wr + i * 16 + q * 4 + r;
            if (pos < o + c) {
#pragma unroll
                for (int j = 0; j < 4; j++)
                    ppart[((size_t)s * NPAD + pos) * HD + wc + j * 16 + m16] = acc[i][j][r];
            }
        }
}

__global__ void pv_reduce(const float* __restrict__ ppart, const float* __restrict__ aga,
                          const int* __restrict__ list, ushort* __restrict__ ctx16) {
    int pos = blockIdx.x, h = threadIdx.x;  // 128
    float g = aga[list[pos]];
    float a = 0.f;
#pragma unroll
    for (int s = 0; s < 4; s++) a += ppart[((size_t)s * NPAD + pos) * HD + h];
    ctx16[(size_t)pos * HD + h] = f2b(a * g);
}

// ---------------- o: MFMA ctx@o_w, dense bf16 per-pair rows ----------------
__global__ __launch_bounds__(256) void o_mfma(
    const ushort* __restrict__ ctx16, const ushort* __restrict__ owt,
    const int* __restrict__ meta, ushort* __restrict__ Ofb) {
    int e = blockIdx.z;
    int o = meta[96 + e], c = meta[97 + e] - o;
    int m0 = blockIdx.x * 64;
    if (m0 >= c) return;
    int n0 = blockIdx.y * 128;
    __shared__ __align__(16) short As[2][64 * BSTR];
    __shared__ __align__(16) short Bs[2][128 * BSTR];
    int tid = threadIdx.x, w = tid >> 6, lane = tid & 63;
    int sr = lane >> 2, sc = (lane & 3) * 8;
    const ushort* ap = ctx16 + (size_t)(o + m0 + w * 16 + sr) * HD + sc;
    const ushort* bp0 = owt + (size_t)e * D * HD + (size_t)(n0 + w * 32 + sr) * HD + sc;
    const ushort* bp1 = bp0 + (size_t)16 * HD;
    int wr = (w >> 1) * 32, wc = (w & 1) * 64;
    int m16 = lane & 15, q = lane >> 4;
    f32x4 acc[2][4] = {};
    gll(ap, &As[0][w * 512]); gll(bp0, &Bs[0][w * 1024]); gll(bp1, &Bs[0][w * 1024 + 512]);
    __syncthreads();
    int cur = 0;
    for (int k = 1; k < 4; k++) {
        int nxt = cur ^ 1;
        gll(ap + k * 32, &As[nxt][w * 512]);
        gll(bp0 + k * 32, &Bs[nxt][w * 1024]);
        gll(bp1 + k * 32, &Bs[nxt][w * 1024 + 512]);
        mfma_step(As[cur], Bs[cur], wr, wc, m16, q, acc);
        __syncthreads();
        cur = nxt;
    }
    mfma_step(As[cur], Bs[cur], wr, wc, m16, q, acc);
#pragma unroll
    for (int i = 0; i < 2; i++)
#pragma unroll
        for (int r = 0; r < 4; r++) {
            int pos = o + m0 + wr + i * 16 + q * 4 + r;
            if (pos < o + c) {
#pragma unroll
                for (int j = 0; j < 4; j++)
                    Ofb[(size_t)pos * D + n0 + wc + j * 16 + m16] = f2b(acc[i][j][r]);
            }
        }
}

// ---------------- attn combine ----------------
__global__ void attn_combine(const float* __restrict__ src, const float* __restrict__ ob,
                             const int* __restrict__ aidx, const float* __restrict__ aga,
                             const int* __restrict__ ainv, const ushort* __restrict__ Ofb,
                             float* __restrict__ x1) {
    int t = blockIdx.x, tid = threadIdx.x;
    int e0 = aidx[t * 2], e1 = aidx[t * 2 + 1];
    float g0 = aga[t * 2], g1 = aga[t * 2 + 1];
    int p0 = ainv[t * 2], p1 = ainv[t * 2 + 1];
#pragma unroll
    for (int i = 0; i < 4; i++) {
        int d = tid + i * 256;
        x1[(size_t)t * D + d] = src[(size_t)t * D + d]
                              + g0 * ob[e0 * D + d] + g1 * ob[e1 * D + d]
                              + b2f(Ofb[(size_t)p0 * D + d]) + b2f(Ofb[(size_t)p1 * D + d]);
    }
}

// ---------------- FFN GEMM1: Hb = g*relu(xn2 @ W1 + b1) ----------------
__global__ __launch_bounds__(256) void ffn_mfma1(
    const ushort* __restrict__ xnb2, const ushort* __restrict__ w1t,
    const float* __restrict__ b1, const int* __restrict__ meta,
    const int* __restrict__ list, const float* __restrict__ fga,
    ushort* __restrict__ Hb) {
    int e = blockIdx.z;
    int o = meta[16 + e], c = meta[e];
    int m0 = blockIdx.x * 64;
    if (m0 >= c) return;
    int n0 = blockIdx.y * 128;
    __shared__ __align__(16) short As[2][64 * BSTR];
    __shared__ __align__(16) short Bs[2][128 * BSTR];
    int tid = threadIdx.x, w = tid >> 6, lane = tid & 63;
    int sr = lane >> 2, sc = (lane & 3) * 8;
    int ri = o + m0 + w * 16 + sr; if (ri > NPAIR - 1) ri = NPAIR - 1;
    const ushort* ap = xnb2 + (size_t)(list[ri] >> 1) * D + sc;
    const ushort* bp0 = w1t + ((size_t)e * FH + n0 + w * 32 + sr) * D + sc;
    const ushort* bp1 = bp0 + (size_t)16 * D;
    int wr = (w >> 1) * 32, wc = (w & 1) * 64;
    int m16 = lane & 15, q = lane >> 4;
    f32x4 acc[2][4] = {};
    gll(ap, &As[0][w * 512]); gll(bp0, &Bs[0][w * 1024]); gll(bp1, &Bs[0][w * 1024 + 512]);
    __syncthreads();
    int cur = 0;
    for (int k = 1; k < 32; k++) {
        int nxt = cur ^ 1;
        gll(ap + k * 32, &As[nxt][w * 512]);
        gll(bp0 + k * 32, &Bs[nxt][w * 1024]);
        gll(bp1 + k * 32, &Bs[nxt][w * 1024 + 512]);
        mfma_step(As[cur], Bs[cur], wr, wc, m16, q, acc);
        __syncthreads();
        cur = nxt;
    }
    mfma_step(As[cur], Bs[cur], wr, wc, m16, q, acc);
#pragma unroll
    for (int i = 0; i < 2; i++)
#pragma unroll
        for (int r = 0; r < 4; r++) {
            int pos = o + m0 + wr + i * 16 + q * 4 + r;
            if (pos < o + c) {
                float g = fga[list[pos]];
#pragma unroll
                for (int j = 0; j < 4; j++) {
                    int n = n0 + wc + j * 16 + m16;
                    Hb[(size_t)pos * FH + n] = f2b(g * fmaxf(acc[i][j][r] + b1[e * FH + n], 0.f));
                }
            }
        }
}

// ---------------- FFN GEMM2: Of2b[pos] = Hb @ W2 (dense bf16 rows) ----------------
__global__ __launch_bounds__(256) void ffn_mfma2(
    const ushort* __restrict__ Hb, const ushort* __restrict__ w2t,
    const int* __restrict__ meta, ushort* __restrict__ Of2b) {
    int e = blockIdx.z;
    int o = meta[16 + e], c = meta[e];
    int m0 = blockIdx.x * 64;
    if (m0 >= c) return;
    int n0 = blockIdx.y * 128;
    __shared__ __align__(16) short As[2][64 * BSTR];
    __shared__ __align__(16) short Bs[2][128 * BSTR];
    int tid = threadIdx.x, w = tid >> 6, lane = tid & 63;
    int sr = lane >> 2, sc = (lane & 3) * 8;
    const ushort* ap = Hb + (size_t)(o + m0 + w * 16 + sr) * FH + sc;
    const ushort* bp0 = w2t + ((size_t)e * D + n0 + w * 32 + sr) * FH + sc;
    const ushort* bp1 = bp0 + (size_t)16 * FH;
    int wr = (w >> 1) * 32, wc = (w & 1) * 64;
    int m16 = lane & 15, q = lane >> 4;
    f32x4 acc[2][4] = {};
    gll(ap, &As[0][w * 512]); gll(bp0, &Bs[0][w * 1024]); gll(bp1, &Bs[0][w * 1024 + 512]);
    __syncthreads();
    int cur = 0;
    for (int k = 1; k < 16; k++) {
        int nxt = cur ^ 1;
        gll(ap + k * 32, &As[nxt][w * 512]);
        gll(bp0 + k * 32, &Bs[nxt][w * 1024]);
        gll(bp1 + k * 32, &Bs[nxt][w * 1024 + 512]);
        mfma_step(As[cur], Bs[cur], wr, wc, m16, q, acc);
        __syncthreads();
        cur = nxt;
    }
    mfma_step(As[cur], Bs[cur], wr, wc, m16, q, acc);
#pragma unroll
    for (int i = 0; i < 2; i++)
#pragma unroll
        for (int r = 0; r < 4; r++) {
            int pos = o + m0 + wr + i * 16 + q * 4 + r;
            if (pos < o + c) {
#pragma unroll
                for (int j = 0; j < 4; j++)
                    Of2b[(size_t)pos * D + n0 + wc + j * 16 + m16] = f2b(acc[i][j][r]);
            }
        }
}

// ---------------- FFN combine ----------------
__global__ void ffn_combine(const float* __restrict__ x1, const float* __restrict__ b2,
                            const int* __restrict__ fidx, const float* __restrict__ fga,
                            const int* __restrict__ finv, const ushort* __restrict__ Of2b,
                            float* __restrict__ out) {
    int t = blockIdx.x, tid = threadIdx.x;
    int e0 = fidx[t * 2], e1 = fidx[t * 2 + 1];
    float g0 = fga[t * 2], g1 = fga[t * 2 + 1];
    int p0 = finv[t * 2], p1 = finv[t * 2 + 1];
#pragma unroll
    for (int i = 0; i < 4; i++) {
        int d = tid + i * 256;
        out[(size_t)t * D + d] = x1[(size_t)t * D + d]
                               + g0 * b2[e0 * D + d] + g1 * b2[e1 * D + d]
                               + b2f(Of2b[(size_t)p0 * D + d]) + b2f(Of2b[(size_t)p1 * D + d]);
    }
}

extern "C" void kernel_launch(void* const* d_in, const int* in_sizes, int n_in,
                              void* d_out, int out_size, void* d_ws, size_t ws_size,
                              hipStream_t stream) {
    const float* src   = (const float*)d_in[0];
    const float* ln1_w = (const float*)d_in[1];
    const float* ln1_b = (const float*)d_in[2];
    const float* ln2_w = (const float*)d_in[3];
    const float* ln2_b = (const float*)d_in[4];
    const float* agw   = (const float*)d_in[5];
    const float* qw    = (const float*)d_in[6];
    const float* qb    = (const float*)d_in[7];
    const float* kw    = (const float*)d_in[8];
    const float* kb    = (const float*)d_in[9];
    const float* vw    = (const float*)d_in[10];
    const float* vb    = (const float*)d_in[11];
    const float* ow    = (const float*)d_in[12];
    const float* ob    = (const float*)d_in[13];
    const float* rel   = (const float*)d_in[14];
    const float* fgw   = (const float*)d_in[15];
    const float* w1    = (const float*)d_in[16];
    const float* b1    = (const float*)d_in[17];
    const float* w2    = (const float*)d_in[18];
    const float* b2    = (const float*)d_in[19];
    float* out = (float*)d_out;

    char* p = (char*)d_ws;
    float* xn1  = (float*)p; p += (size_t)NTOK * D * 4;               // LN out fp32 (router)
    float* x1   = (float*)p; p += (size_t)NTOK * D * 4;
    char*  sreg = p;         p += (size_t)NPAD * SEQ * 4;             // 34.1 MB
    float*  Sbuf = (float*)sreg;                                      // attn: scores (fp32) / P (bf16 in place)
    ushort* Pb   = (ushort*)sreg;                                     // bf16 P, row stride PROW
    ushort* Ofb  = (ushort*)sreg;                                     // attn: o rows (17 MB)
    ushort* w1t  = (ushort*)sreg;                                     // FFN: 16.78 MB
    ushort* w2t  = (ushort*)(sreg + (size_t)16777216);                // FFN: 16.78 MB
    char*  reg  = p;         p += (size_t)NPAD * 128 * 6 + (size_t)NPAIR * RSTRIDE * 4;
    ushort* ctx16 = (ushort*)reg;                                     // 2.13 MB (bf16 ctx)
    ushort* Qg   = (ushort*)(reg + (size_t)NPAD * 128 * 4);           // 2.13 MB
    float*  Rbuf = (float*)(reg + (size_t)NPAD * 128 * 6);            // 4.33 MB
    ushort* Hb   = (ushort*)reg;                                      // FFN hidden (8.52 MB)
    char*  arena = p;        p += (size_t)4 * NPAD * 128 * 4;         // 17.04 MB
    float*  kpart = (float*)arena;
    float*  vpart = (float*)(arena + (size_t)4 * NTOK * HD * 4);
    float*  qpart = (float*)arena;
    float*  ppart = (float*)arena;
    ushort* Of2b  = (ushort*)arena;
    ushort* kb16 = (ushort*)p; p += (size_t)NTOK * HD * 2;
    float* vbf  = (float*)p; p += (size_t)NTOK * HD * 4;
    ushort* vt16 = (ushort*)p; p += (size_t)NTOK * HD * 2;
    ushort* kwt = (ushort*)p; p += (size_t)HD * D * 2;
    ushort* vwt = (ushort*)p; p += (size_t)HD * D * 2;
    ushort* qwt = (ushort*)p; p += (size_t)EA * HD * D * 2;
    ushort* owt = (ushort*)p; p += (size_t)EA * D * HD * 2;
    ushort* relb = (ushort*)p; p += (size_t)RNUM * HD * 2 + 256;
    int*   aidx = (int*)p;   p += NPAIR * 4;
    float* aga  = (float*)p; p += NPAIR * 4;
    int*   fidx = (int*)p;   p += NPAIR * 4;
    float* fga  = (float*)p; p += NPAIR * 4;
    int*   ameta = (int*)p;  p += 128 * 4;
    int*   alist = (int*)p;  p += NPAIR * 4;
    int*   ainv = (int*)p;   p += NPAIR * 4;
    int*   fmeta = (int*)p;  p += 64 * 4;
    int*   flist = (int*)p;  p += NPAIR * 4;
    int*   finv = (int*)p;   p += NPAIR * 4;
    ushort* xnb = (ushort*)p; p += (size_t)NTOK * D * 2;              // bf16 LN out (GEMM A operand)
    float* xn2 = xn1;

    // ---- attention ----
    ln_kernel<<<NTOK, 256, 0, stream>>>(src, ln1_w, ln1_b, xn1, xnb);
    router_kernel<EA><<<NTOK, 64, 0, stream>>>(xn1, agw, aidx, aga);
    abin_zero<<<1, 128, 0, stream>>>(ameta);
    abin_count<<<NPAIR / 256, 256, 0, stream>>>(aidx, ameta);
    abin_scan<<<1, 64, 0, stream>>>(ameta);
    abin_scatter<<<NPAIR / 256, 256, 0, stream>>>(aidx, ameta, alist, ainv);
    convT_kernel<1024, 128><<<dim3(32, 4, 1), 256, 0, stream>>>(kw, kwt);
    convT_kernel<1024, 128><<<dim3(32, 4, 1), 256, 0, stream>>>(vw, vwt);
    convT_kernel<1024, 128><<<dim3(32, 4, EA), 256, 0, stream>>>(qw, qwt);
    convT_kernel<128, 1024><<<dim3(4, 32, EA), 256, 0, stream>>>(ow, owt);
    conv_kernel<<<(RNUM * HD + 255) / 256, 256, 0, stream>>>(rel, relb, RNUM * HD);
    kv_mfma<<<dim3(64, 4, 2), 256, 0, stream>>>(xnb, kwt, vwt, kpart, vpart);
    kv_reduce<<<NTOK, 128, 0, stream>>>(kpart, vpart, kb, vb, kb16, vbf);
    convT_kernel<1024, 128><<<dim3(32, 4, 4), 256, 0, stream>>>(vbf, vt16);
    q_mfma<<<dim3(40, 4, EA), 256, 0, stream>>>(xnb, qwt, ameta, alist, qpart);
    q_reduce<<<NPAIR, 128, 0, stream>>>(qpart, qb, aidx, alist, Qg);
    rel_mfma<<<dim3(NPAIR / 64, 2), 256, 0, stream>>>(Qg, relb, Rbuf);
    s_mfma<<<dim3(12, 8, 32), 256, 0, stream>>>(Qg, kb16, Rbuf, ameta, alist, Sbuf);
    softmax_kernel<<<NPAIR, 256, 0, stream>>>(Sbuf);
    pv_mfma<<<dim3(12, 4, 32), 256, 0, stream>>>(Pb, vt16, ameta, ppart);
    pv_reduce<<<NPAIR, 128, 0, stream>>>(ppart, aga, alist, ctx16);
    o_mfma<<<dim3(40, 8, EA), 256, 0, stream>>>(ctx16, owt, ameta, Ofb);
    attn_combine<<<NTOK, 256, 0, stream>>>(src, ob, aidx, aga, ainv, Ofb, x1);

    // ---- FFN ----
    ln_kernel<<<NTOK, 256, 0, stream>>>(x1, ln2_w, ln2_b, xn2, xnb);
    router_kernel<EF><<<NTOK, 64, 0, stream>>>(xn2, fgw, fidx, fga);
    bin_zero<<<1, 64, 0, stream>>>(fmeta);
    bin_count<<<NPAIR / 256, 256, 0, stream>>>(fidx, fmeta);
    bin_scan<<<1, 64, 0, stream>>>(fmeta);
    bin_scatter<<<NPAIR / 256, 256, 0, stream>>>(fidx, fmeta, flist, finv);
    convT_kernel<1024, 512><<<dim3(32, 16, EF), 256, 0, stream>>>(w1, w1t);
    convT_kernel<512, 1024><<<dim3(16, 32, EF), 256, 0, stream>>>(w2, w2t);
    ffn_mfma1<<<dim3(20, 4, EF), 256, 0, stream>>>(xnb, w1t, b1, fmeta, flist, fga, Hb);
    ffn_mfma2<<<dim3(20, 8, EF), 256, 0, stream>>>(Hb, w2t, fmeta, Of2b);
    ffn_combine<<<NTOK, 256, 0, stream>>>(x1, b2, fidx, fga, finv, Of2b, out);
}

// Round 2
// 499.891 us; speedup vs baseline: 1.0338x; 1.0204x over previous
//
#include <hip/hip_runtime.h>

#define D 1024
#define HD 128
#define EA 8
#define EF 16
#define FH 512
#define MAXPOS 64
#define RNUM 129
#define RSTRIDE 132
#define SEQ 1024
#define NTOK 4096
#define NPAIR (NTOK * 2)
#define NPAD 8320          // NPAIR + 128 slack
#define LN_EPS 1e-5f
#define QSCALE 0.08838834764831845f
#define BSTR 32            // linear LDS row stride in bf16 elems (global_load_lds needs linear)
#define PROW 2048          // bf16 P row stride in ushorts (= SEQ*4B slot)

typedef __attribute__((ext_vector_type(8))) short bf16x8;
typedef __attribute__((ext_vector_type(4))) float f32x4;
typedef __attribute__((ext_vector_type(8))) unsigned short u16x8;

__device__ inline ushort f2b(float f) {
    union { float f; unsigned u; } v; v.f = f;
    unsigned r = (v.u + 0x7fffu + ((v.u >> 16) & 1u)) >> 16;
    return (ushort)r;
}
__device__ inline float b2f(ushort u) {
    union { unsigned u; float f; } v; v.u = (unsigned)u << 16; return v.f;
}

// async global->LDS, 16B per lane, dest = wave-uniform base + lane*16
__device__ __forceinline__ void gll(const void* g, void* l) {
    __builtin_amdgcn_global_load_lds((const __attribute__((address_space(1))) void*)g,
                                     (__attribute__((address_space(3))) void*)l, 16, 0, 0);
}
// counted waits: each wave issues exactly 3 global_load_lds per K-step.
__device__ __forceinline__ void wait_vm3() { asm volatile("s_waitcnt vmcnt(3)" ::: "memory"); }
__device__ __forceinline__ void wait_vm0() { asm volatile("s_waitcnt vmcnt(0)" ::: "memory"); }
__device__ __forceinline__ void bar() { __builtin_amdgcn_s_barrier(); }

// one double-buffer compute step: 64x128 tile, wave = 32x64
__device__ inline void mfma_step(const short* Asb, const short* Bsb,
                                 int wr, int wc, int m16, int q, f32x4 (&acc)[2][4]) {
    bf16x8 af[2], bfr[4];
#pragma unroll
    for (int i = 0; i < 2; i++) af[i] = *(const bf16x8*)&Asb[(wr + i * 16 + m16) * BSTR + q * 8];
#pragma unroll
    for (int j = 0; j < 4; j++) bfr[j] = *(const bf16x8*)&Bsb[(wc + j * 16 + m16) * BSTR + q * 8];
#pragma unroll
    for (int i = 0; i < 2; i++)
#pragma unroll
        for (int j = 0; j < 4; j++)
            acc[i][j] = __builtin_amdgcn_mfma_f32_16x16x32_bf16(af[i], bfr[j], acc[i][j], 0, 0, 0);
}

// depth-2 counted-vmcnt K-loop (T3/T4-lite). Each iteration:
//   wait step-k loads (leave step-k+1 in flight) -> barrier -> MFMA(cur)
//   -> barrier (reads of cur done) -> issue step-k+2 into cur.
#define KLOOP(NK, AP, BP0, BP1, STRIDE)                                          \
    gll(AP, &As[0][w * 512]); gll(BP0, &Bs[0][w * 1024]); gll(BP1, &Bs[0][w * 1024 + 512]); \
    gll(AP + STRIDE, &As[1][w * 512]); gll(BP0 + STRIDE, &Bs[1][w * 1024]);      \
    gll(BP1 + STRIDE, &Bs[1][w * 1024 + 512]);                                   \
    {                                                                            \
        int cur = 0;                                                             \
        for (int k = 0; k < NK; k++) {                                           \
            if (k < NK - 1) wait_vm3(); else wait_vm0();                         \
            bar();                                                               \
            mfma_step(As[cur], Bs[cur], wr, wc, m16, q, acc);                    \
            if (k + 2 < NK) {                                                    \
                bar();                                                           \
                gll(AP + (k + 2) * STRIDE, &As[cur][w * 512]);                   \
                gll(BP0 + (k + 2) * STRIDE, &Bs[cur][w * 1024]);                 \
                gll(BP1 + (k + 2) * STRIDE, &Bs[cur][w * 1024 + 512]);           \
            }                                                                    \
            cur ^= 1;                                                            \
        }                                                                        \
    }

// ---------------- LayerNorm (fp32 out for router + bf16 out for GEMMs) ----------------
__global__ void ln_kernel(const float* __restrict__ x, const float* __restrict__ w,
                          const float* __restrict__ b, float* __restrict__ y,
                          ushort* __restrict__ yb) {
    int row = blockIdx.x;
    const float* xr = x + (size_t)row * D;
    float v[4];
    float s = 0.f, s2 = 0.f;
#pragma unroll
    for (int i = 0; i < 4; i++) {
        v[i] = xr[threadIdx.x + i * 256];
        s += v[i]; s2 += v[i] * v[i];
    }
#pragma unroll
    for (int off = 32; off; off >>= 1) { s += __shfl_down(s, off); s2 += __shfl_down(s2, off); }
    __shared__ float red0[4], red1[4];
    int wave = threadIdx.x >> 6, lane = threadIdx.x & 63;
    if (lane == 0) { red0[wave] = s; red1[wave] = s2; }
    __syncthreads();
    float ts = red0[0] + red0[1] + red0[2] + red0[3];
    float ts2 = red1[0] + red1[1] + red1[2] + red1[3];
    float mu = ts * (1.f / D);
    float var = ts2 * (1.f / D) - mu * mu;
    float inv = rsqrtf(var + LN_EPS);
#pragma unroll
    for (int i = 0; i < 4; i++) {
        int d = threadIdx.x + i * 256;
        float o = (v[i] - mu) * inv * w[d] + b[d];
        y[(size_t)row * D + d] = o;
        yb[(size_t)row * D + d] = f2b(o);
    }
}

// ---------------- Router ----------------
template <int E>
__global__ void router_kernel(const float* __restrict__ xn, const float* __restrict__ gw,
                              int* __restrict__ idx, float* __restrict__ gate) {
    int t = blockIdx.x;
    int lane = threadIdx.x;  // block=64
    float acc[E];
#pragma unroll
    for (int e = 0; e < E; e++) acc[e] = 0.f;
    const float* xr = xn + (size_t)t * D;
    for (int d = lane; d < D; d += 64) {
        float xv = xr[d];
#pragma unroll
        for (int e = 0; e < E; e++) acc[e] += xv * gw[d * E + e];
    }
#pragma unroll
    for (int e = 0; e < E; e++) {
#pragma unroll
        for (int off = 32; off; off >>= 1) acc[e] += __shfl_down(acc[e], off);
    }
    if (lane == 0) {
        float v0 = -1e30f, v1 = -1e30f;
        int i0 = 0, i1 = 0;
#pragma unroll
        for (int e = 0; e < E; e++) {
            float a = acc[e];
            if (a > v0) { v1 = v0; i1 = i0; v0 = a; i0 = e; }
            else if (a > v1) { v1 = a; i1 = e; }
        }
        float g0 = 1.f / (1.f + expf(v1 - v0));
        idx[t * 2] = i0; idx[t * 2 + 1] = i1;
        gate[t * 2] = g0; gate[t * 2 + 1] = 1.f - g0;
    }
}

// ---------------- meta zeroing (attn + ffn merged) ----------------
__global__ void zero_meta(int* __restrict__ ameta, int* __restrict__ fmeta) {
    if (threadIdx.x < 105) ameta[threadIdx.x] = 0;
    if (threadIdx.x < 48) fmeta[threadIdx.x] = 0;
}

// ---------------- Attention binning: 32 bins keyed (expert*4 + batch) ----------------
__global__ void abin_count(const int* __restrict__ aidx, int* __restrict__ meta) {
    int i = blockIdx.x * 256 + threadIdx.x;
    if (i < NPAIR) {
        int e = aidx[i];
        int b = (i >> 1) >> 10;
        atomicAdd(&meta[e * 4 + b], 1);
    }
}
__global__ void abin_scan(int* __restrict__ meta) {
    if (threadIdx.x == 0 && blockIdx.x == 0) {
        int s = 0;
        for (int bin = 0; bin < 32; bin++) {
            if ((bin & 3) == 0) meta[96 + (bin >> 2)] = s;
            meta[32 + bin] = s; meta[64 + bin] = s; s += meta[bin];
        }
        meta[96 + 8] = s;
    }
}
__global__ void abin_scatter(const int* __restrict__ aidx, int* __restrict__ meta,
                             int* __restrict__ list, int* __restrict__ inv) {
    int i = blockIdx.x * 256 + threadIdx.x;
    if (i < NPAIR) {
        int e = aidx[i];
        int b = (i >> 1) >> 10;
        int pos = atomicAdd(&meta[64 + e * 4 + b], 1);
        list[pos] = i;
        inv[i] = pos;
    }
}

// ---------------- FFN binning ----------------
__global__ void bin_count(const int* __restrict__ fidx, int* __restrict__ meta) {
    int i = blockIdx.x * 256 + threadIdx.x;
    if (i < NPAIR) atomicAdd(&meta[fidx[i]], 1);
}
__global__ void bin_scan(int* __restrict__ meta) {
    if (threadIdx.x == 0 && blockIdx.x == 0) {
        int s = 0;
        for (int e = 0; e < EF; e++) { meta[16 + e] = s; meta[32 + e] = s; s += meta[e]; }
    }
}
__global__ void bin_scatter(const int* __restrict__ fidx, int* __restrict__ meta,
                            int* __restrict__ list, int* __restrict__ inv) {
    int i = blockIdx.x * 256 + threadIdx.x;
    if (i < NPAIR) {
        int e = fidx[i];
        int pos = atomicAdd(&meta[32 + e], 1);
        list[pos] = i;
        inv[i] = pos;
    }
}

// ---------------- transpose-convert [E][R][C] fp32 -> [E][C][R] bf16 ----------------
template <int R, int C>
__global__ void convT_kernel(const float* __restrict__ in, ushort* __restrict__ out) {
    int e = blockIdx.z;
    int r0 = blockIdx.x * 32, c0 = blockIdx.y * 32;
    __shared__ float tile[32][33];
    int tx = threadIdx.x & 31, ty = threadIdx.x >> 5;  // 256 thr
    const float* src = in + (size_t)e * R * C;
#pragma unroll
    for (int i = 0; i < 32; i += 8)
        tile[ty + i][tx] = src[(size_t)(r0 + ty + i) * C + c0 + tx];
    __syncthreads();
    ushort* dst = out + (size_t)e * C * R;
#pragma unroll
    for (int i = 0; i < 32; i += 8)
        dst[(size_t)(c0 + ty + i) * R + r0 + tx] = f2b(tile[tx][ty + i]);
}

// elementwise fp32 -> bf16 (small arrays)
__global__ void conv_kernel(const float* __restrict__ in, ushort* __restrict__ out, int n) {
    int i = blockIdx.x * 256 + threadIdx.x;
    if (i < n) out[i] = f2b(in[i]);
}

// ---- staging geometry (shared by all GEMMs):
//   wave w stages A rows [w*16, w*16+16) and B rows [w*32, w*32+32) of the tile,
//   one 1KB global_load_lds issue covers 16 rows x 64B; lane l -> row l>>2, byte (l&3)*16.

// ---------------- kv: split-K MFMA, dense per-split partials ----------------
__global__ __launch_bounds__(256) void kv_mfma(
    const ushort* __restrict__ xnb, const ushort* __restrict__ kwt,
    const ushort* __restrict__ vwt, float* __restrict__ kpart, float* __restrict__ vpart) {
    const ushort* W = blockIdx.z ? vwt : kwt;
    float* outp = blockIdx.z ? vpart : kpart;
    int m0 = blockIdx.x * 64;
    int s = blockIdx.y;
    int kbase = s * 256;
    __shared__ __align__(16) short As[2][64 * BSTR];
    __shared__ __align__(16) short Bs[2][128 * BSTR];
    int tid = threadIdx.x, w = tid >> 6, lane = tid & 63;
    int sr = lane >> 2, sc = (lane & 3) * 8;
    const ushort* ap = xnb + (size_t)(m0 + w * 16 + sr) * D + kbase + sc;
    const ushort* bp0 = W + (size_t)(w * 32 + sr) * D + kbase + sc;
    const ushort* bp1 = bp0 + (size_t)16 * D;
    int wr = (w >> 1) * 32, wc = (w & 1) * 64;
    int m16 = lane & 15, q = lane >> 4;
    f32x4 acc[2][4] = {};
    KLOOP(8, ap, bp0, bp1, 32)
#pragma unroll
    for (int i = 0; i < 2; i++)
#pragma unroll
        for (int r = 0; r < 4; r++) {
            int m = m0 + wr + i * 16 + q * 4 + r;
#pragma unroll
            for (int j = 0; j < 4; j++)
                outp[((size_t)s * NTOK + m) * HD + wc + j * 16 + m16] = acc[i][j][r];
        }
}

__global__ void kv_reduce(const float* __restrict__ kpart, const float* __restrict__ vpart,
                          const float* __restrict__ kb, const float* __restrict__ vb,
                          ushort* __restrict__ kb16, float* __restrict__ vbf) {
    int t = blockIdx.x, h = threadIdx.x;  // 128
    float ka = kb[h], va = vb[h];
#pragma unroll
    for (int s = 0; s < 4; s++) {
        ka += kpart[((size_t)s * NTOK + t) * HD + h];
        va += vpart[((size_t)s * NTOK + t) * HD + h];
    }
    kb16[(size_t)t * HD + h] = f2b(ka);
    vbf[(size_t)t * HD + h] = va;
}

// ---------------- q: split-K MFMA, indirect A, dense partials ----------------
__global__ __launch_bounds__(256) void q_mfma(
    const ushort* __restrict__ xnb, const ushort* __restrict__ qwt,
    const int* __restrict__ meta, const int* __restrict__ list, float* __restrict__ qpart) {
    int e = blockIdx.z;
    int o = meta[96 + e], c = meta[97 + e] - o;
    int m0 = blockIdx.x * 64;
    if (m0 >= c) return;
    int s = blockIdx.y;
    int kbase = s * 256;
    __shared__ __align__(16) short As[2][64 * BSTR];
    __shared__ __align__(16) short Bs[2][128 * BSTR];
    int tid = threadIdx.x, w = tid >> 6, lane = tid & 63;
    int sr = lane >> 2, sc = (lane & 3) * 8;
    int ri = o + m0 + w * 16 + sr; if (ri > NPAIR - 1) ri = NPAIR - 1;
    const ushort* ap = xnb + (size_t)(list[ri] >> 1) * D + kbase + sc;
    const ushort* bp0 = qwt + (size_t)e * HD * D + (size_t)(w * 32 + sr) * D + kbase + sc;
    const ushort* bp1 = bp0 + (size_t)16 * D;
    int wr = (w >> 1) * 32, wc = (w & 1) * 64;
    int m16 = lane & 15, q = lane >> 4;
    f32x4 acc[2][4] = {};
    KLOOP(8, ap, bp0, bp1, 32)
#pragma unroll
    for (int i = 0; i < 2; i++)
#pragma unroll
        for (int r = 0; r < 4; r++) {
            int pos = o + m0 + wr + i * 16 + q * 4 + r;
            if (pos < o + c) {
#pragma unroll
                for (int j = 0; j < 4; j++)
                    qpart[((size_t)s * NPAD + pos) * HD + wc + j * 16 + m16] = acc[i][j][r];
            }
        }
}

__global__ void q_reduce(const float* __restrict__ qpart, const float* __restrict__ qb,
                         const int* __restrict__ aidx, const int* __restrict__ list,
                         ushort* __restrict__ Qg) {
    int pos = blockIdx.x, h = threadIdx.x;  // 128
    int e = aidx[list[pos]];
    float a = qb[e * HD + h];
#pragma unroll
    for (int s = 0; s < 4; s++) a += qpart[((size_t)s * NPAD + pos) * HD + h];
    Qg[(size_t)pos * HD + h] = f2b(a * QSCALE);
}

// ---------------- rel: MFMA GEMM  R[pos][r] = Qg[pos] . rel[r] ----------------
__global__ __launch_bounds__(256) void rel_mfma(
    const ushort* __restrict__ Qg, const ushort* __restrict__ relb,
    float* __restrict__ R) {
    int m0 = blockIdx.x * 64;
    int n0 = blockIdx.y * 128;
    __shared__ __align__(16) short As[2][64 * BSTR];
    __shared__ __align__(16) short Bs[2][128 * BSTR];
    int tid = threadIdx.x, w = tid >> 6, lane = tid & 63;
    int sr = lane >> 2, sc = (lane & 3) * 8;
    const ushort* ap = Qg + (size_t)(m0 + w * 16 + sr) * HD + sc;
    int r0 = n0 + w * 32 + sr;      if (r0 > RNUM - 1) r0 = RNUM - 1;
    int r1 = n0 + w * 32 + 16 + sr; if (r1 > RNUM - 1) r1 = RNUM - 1;
    const ushort* bp0 = relb + (size_t)r0 * HD + sc;
    const ushort* bp1 = relb + (size_t)r1 * HD + sc;
    int wr = (w >> 1) * 32, wc = (w & 1) * 64;
    int m16 = lane & 15, q = lane >> 4;
    f32x4 acc[2][4] = {};
    KLOOP(4, ap, bp0, bp1, 32)
#pragma unroll
    for (int i = 0; i < 2; i++)
#pragma unroll
        for (int r = 0; r < 4; r++) {
            int pos = m0 + wr + i * 16 + q * 4 + r;
#pragma unroll
            for (int j = 0; j < 4; j++) {
                int n = n0 + wc + j * 16 + m16;
                if (n < RNUM) R[(size_t)pos * RSTRIDE + n] = acc[i][j][r];
            }
        }
}

// ---------------- s: MFMA QK^T + rel bias, fp32 S out ----------------
__global__ __launch_bounds__(256) void s_mfma(
    const ushort* __restrict__ Qg, const ushort* __restrict__ kb16,
    const float* __restrict__ R, const int* __restrict__ meta,
    const int* __restrict__ list, float* __restrict__ S) {
    int bin = blockIdx.z;
    int o = meta[32 + bin], c = meta[bin];
    int m0 = blockIdx.x * 64;
    if (m0 >= c) return;
    int b = bin & 3;
    int n0 = blockIdx.y * 128;
    __shared__ __align__(16) short As[2][64 * BSTR];
    __shared__ __align__(16) short Bs[2][128 * BSTR];
    int tid = threadIdx.x, w = tid >> 6, lane = tid & 63;
    int sr = lane >> 2, sc = (lane & 3) * 8;
    const ushort* ap = Qg + (size_t)(o + m0 + w * 16 + sr) * HD + sc;
    const ushort* bp0 = kb16 + (size_t)b * SEQ * HD + (size_t)(n0 + w * 32 + sr) * HD + sc;
    const ushort* bp1 = bp0 + (size_t)16 * HD;
    int wr = (w >> 1) * 32, wc = (w & 1) * 64;
    int m16 = lane & 15, q = lane >> 4;
    f32x4 acc[2][4] = {};
    KLOOP(4, ap, bp0, bp1, 32)
#pragma unroll
    for (int i = 0; i < 2; i++)
#pragma unroll
        for (int r = 0; r < 4; r++) {
            int pos = o + m0 + wr + i * 16 + q * 4 + r;
            if (pos < o + c) {
                int qpos = (list[pos] >> 1) & (SEQ - 1);
                const float* Rrow = R + (size_t)pos * RSTRIDE;
                float* sr_ = S + (size_t)pos * SEQ;
#pragma unroll
                for (int j = 0; j < 4; j++) {
                    int key = n0 + wc + j * 16 + m16;
                    int rix = key - qpos;
                    rix = (rix < -MAXPOS ? -MAXPOS : (rix > MAXPOS ? MAXPOS : rix)) + MAXPOS;
                    sr_[key] = acc[i][j][r] + Rrow[rix];
                }
            }
        }
}

// ---------------- Row softmax: fp32 S in, bf16 P out (in place, same row slot) ----------------
__global__ __launch_bounds__(256) void softmax_kernel(float* __restrict__ S) {
    int row = blockIdx.x;
    float4* sr = (float4*)(S + (size_t)row * SEQ);
    float4 v = sr[threadIdx.x];
    float m = fmaxf(fmaxf(v.x, v.y), fmaxf(v.z, v.w));
#pragma unroll
    for (int off = 32; off; off >>= 1) m = fmaxf(m, __shfl_down(m, off));
    __shared__ float red0[4], red1[4];
    int wave = threadIdx.x >> 6, lane = threadIdx.x & 63;
    if (lane == 0) red0[wave] = m;
    __syncthreads();
    m = fmaxf(fmaxf(red0[0], red0[1]), fmaxf(red0[2], red0[3]));
    v.x = __expf(v.x - m); v.y = __expf(v.y - m);
    v.z = __expf(v.z - m); v.w = __expf(v.w - m);
    float s = v.x + v.y + v.z + v.w;
#pragma unroll
    for (int off = 32; off; off >>= 1) s += __shfl_down(s, off);
    if (lane == 0) red1[wave] = s;
    __syncthreads();
    float inv = 1.f / (red1[0] + red1[1] + red1[2] + red1[3]);
    // all reads of this row completed before the preceding barrier; safe in-place bf16 write
    ushort* pr = (ushort*)(S + (size_t)row * SEQ);
    ushort4 p4 = { f2b(v.x * inv), f2b(v.y * inv), f2b(v.z * inv), f2b(v.w * inv) };
    *(ushort4*)(pr + threadIdx.x * 4) = p4;
}

// ---------------- pv: split-K MFMA P@V (bf16 P direct), dense partials ----------------
__global__ __launch_bounds__(256) void pv_mfma(
    const ushort* __restrict__ Pb, const ushort* __restrict__ vt16,
    const int* __restrict__ meta, float* __restrict__ ppart) {
    int bin = blockIdx.z;
    int o = meta[32 + bin], c = meta[bin];
    int m0 = blockIdx.x * 64;
    if (m0 >= c) return;
    int b = bin & 3;
    int s = blockIdx.y;
    int kbase = s * 256;
    __shared__ __align__(16) short As[2][64 * BSTR];
    __shared__ __align__(16) short Bs[2][128 * BSTR];
    int tid = threadIdx.x, w = tid >> 6, lane = tid & 63;
    int sr = lane >> 2, sc = (lane & 3) * 8;
    const ushort* ap = Pb + (size_t)(o + m0 + w * 16 + sr) * PROW + kbase + sc;
    const ushort* bp0 = vt16 + (size_t)b * HD * SEQ + (size_t)(w * 32 + sr) * SEQ + kbase + sc;
    const ushort* bp1 = bp0 + (size_t)16 * SEQ;
    int wr = (w >> 1) * 32, wc = (w & 1) * 64;
    int m16 = lane & 15, q = lane >> 4;
    f32x4 acc[2][4] = {};
    KLOOP(8, ap, bp0, bp1, 32)
#pragma unroll
    for (int i = 0; i < 2; i++)
#pragma unroll
        for (int r = 0; r < 4; r++) {
            int pos = o + m0 + wr + i * 16 + q * 4 + r;
            if (pos < o + c) {
#pragma unroll
                for (int j = 0; j < 4; j++)
                    ppart[((size_t)s * NPAD + pos) * HD + wc + j * 16 + m16] = acc[i][j][r];
            }
        }
}

__global__ void pv_reduce(const float* __restrict__ ppart, const float* __restrict__ aga,
                          const int* __restrict__ list, ushort* __restrict__ ctx16) {
    int pos = blockIdx.x, h = threadIdx.x;  // 128
    float g = aga[list[pos]];
    float a = 0.f;
#pragma unroll
    for (int s = 0; s < 4; s++) a += ppart[((size_t)s * NPAD + pos) * HD + h];
    ctx16[(size_t)pos * HD + h] = f2b(a * g);
}

// ---------------- o: MFMA ctx@o_w, dense bf16 per-pair rows ----------------
__global__ __launch_bounds__(256) void o_mfma(
    const ushort* __restrict__ ctx16, const ushort* __restrict__ owt,
    const int* __restrict__ meta, ushort* __restrict__ Ofb) {
    int e = blockIdx.z;
    int o = meta[96 + e], c = meta[97 + e] - o;
    int m0 = blockIdx.x * 64;
    if (m0 >= c) return;
    int n0 = blockIdx.y * 128;
    __shared__ __align__(16) short As[2][64 * BSTR];
    __shared__ __align__(16) short Bs[2][128 * BSTR];
    int tid = threadIdx.x, w = tid >> 6, lane = tid & 63;
    int sr = lane >> 2, sc = (lane & 3) * 8;
    const ushort* ap = ctx16 + (size_t)(o + m0 + w * 16 + sr) * HD + sc;
    const ushort* bp0 = owt + (size_t)e * D * HD + (size_t)(n0 + w * 32 + sr) * HD + sc;
    const ushort* bp1 = bp0 + (size_t)16 * HD;
    int wr = (w >> 1) * 32, wc = (w & 1) * 64;
    int m16 = lane & 15, q = lane >> 4;
    f32x4 acc[2][4] = {};
    KLOOP(4, ap, bp0, bp1, 32)
#pragma unroll
    for (int i = 0; i < 2; i++)
#pragma unroll
        for (int r = 0; r < 4; r++) {
            int pos = o + m0 + wr + i * 16 + q * 4 + r;
            if (pos < o + c) {
#pragma unroll
                for (int j = 0; j < 4; j++)
                    Ofb[(size_t)pos * D + n0 + wc + j * 16 + m16] = f2b(acc[i][j][r]);
            }
        }
}

// ---------------- attn combine ----------------
__global__ void attn_combine(const float* __restrict__ src, const float* __restrict__ ob,
                             const int* __restrict__ aidx, const float* __restrict__ aga,
                             const int* __restrict__ ainv, const ushort* __restrict__ Ofb,
                             float* __restrict__ x1) {
    int t = blockIdx.x, tid = threadIdx.x;
    int e0 = aidx[t * 2], e1 = aidx[t * 2 + 1];
    float g0 = aga[t * 2], g1 = aga[t * 2 + 1];
    int p0 = ainv[t * 2], p1 = ainv[t * 2 + 1];
#pragma unroll
    for (int i = 0; i < 4; i++) {
        int d = tid + i * 256;
        x1[(size_t)t * D + d] = src[(size_t)t * D + d]
                              + g0 * ob[e0 * D + d] + g1 * ob[e1 * D + d]
                              + b2f(Ofb[(size_t)p0 * D + d]) + b2f(Ofb[(size_t)p1 * D + d]);
    }
}

// ---------------- FFN GEMM1: Hb = g*relu(xn2 @ W1 + b1) ----------------
__global__ __launch_bounds__(256) void ffn_mfma1(
    const ushort* __restrict__ xnb2, const ushort* __restrict__ w1t,
    const float* __restrict__ b1, const int* __restrict__ meta,
    const int* __restrict__ list, const float* __restrict__ fga,
    ushort* __restrict__ Hb) {
    int e = blockIdx.z;
    int o = meta[16 + e], c = meta[e];
    int m0 = blockIdx.x * 64;
    if (m0 >= c) return;
    int n0 = blockIdx.y * 128;
    __shared__ __align__(16) short As[2][64 * BSTR];
    __shared__ __align__(16) short Bs[2][128 * BSTR];
    int tid = threadIdx.x, w = tid >> 6, lane = tid & 63;
    int sr = lane >> 2, sc = (lane & 3) * 8;
    int ri = o + m0 + w * 16 + sr; if (ri > NPAIR - 1) ri = NPAIR - 1;
    const ushort* ap = xnb2 + (size_t)(list[ri] >> 1) * D + sc;
    const ushort* bp0 = w1t + ((size_t)e * FH + n0 + w * 32 + sr) * D + sc;
    const ushort* bp1 = bp0 + (size_t)16 * D;
    int wr = (w >> 1) * 32, wc = (w & 1) * 64;
    int m16 = lane & 15, q = lane >> 4;
    f32x4 acc[2][4] = {};
    KLOOP(32, ap, bp0, bp1, 32)
#pragma unroll
    for (int i = 0; i < 2; i++)
#pragma unroll
        for (int r = 0; r < 4; r++) {
            int pos = o + m0 + wr + i * 16 + q * 4 + r;
            if (pos < o + c) {
                float g = fga[list[pos]];
#pragma unroll
                for (int j = 0; j < 4; j++) {
                    int n = n0 + wc + j * 16 + m16;
                    Hb[(size_t)pos * FH + n] = f2b(g * fmaxf(acc[i][j][r] + b1[e * FH + n], 0.f));
                }
            }
        }
}

// ---------------- FFN GEMM2: Of2b[pos] = Hb @ W2 (dense bf16 rows) ----------------
__global__ __launch_bounds__(256) void ffn_mfma2(
    const ushort* __restrict__ Hb, const ushort* __restrict__ w2t,
    const int* __restrict__ meta, ushort* __restrict__ Of2b) {
    int e = blockIdx.z;
    int o = meta[16 + e], c = meta[e];
    int m0 = blockIdx.x * 64;
    if (m0 >= c) return;
    int n0 = blockIdx.y * 128;
    __shared__ __align__(16) short As[2][64 * BSTR];
    __shared__ __align__(16) short Bs[2][128 * BSTR];
    int tid = threadIdx.x, w = tid >> 6, lane = tid & 63;
    int sr = lane >> 2, sc = (lane & 3) * 8;
    const ushort* ap = Hb + (size_t)(o + m0 + w * 16 + sr) * FH + sc;
    const ushort* bp0 = w2t + ((size_t)e * D + n0 + w * 32 + sr) * FH + sc;
    const ushort* bp1 = bp0 + (size_t)16 * FH;
    int wr = (w >> 1) * 32, wc = (w & 1) * 64;
    int m16 = lane & 15, q = lane >> 4;
    f32x4 acc[2][4] = {};
    KLOOP(16, ap, bp0, bp1, 32)
#pragma unroll
    for (int i = 0; i < 2; i++)
#pragma unroll
        for (int r = 0; r < 4; r++) {
            int pos = o + m0 + wr + i * 16 + q * 4 + r;
            if (pos < o + c) {
#pragma unroll
                for (int j = 0; j < 4; j++)
                    Of2b[(size_t)pos * D + n0 + wc + j * 16 + m16] = f2b(acc[i][j][r]);
            }
        }
}

// ---------------- FFN combine ----------------
__global__ void ffn_combine(const float* __restrict__ x1, const float* __restrict__ b2,
                            const int* __restrict__ fidx, const float* __restrict__ fga,
                            const int* __restrict__ finv, const ushort* __restrict__ Of2b,
                            float* __restrict__ out) {
    int t = blockIdx.x, tid = threadIdx.x;
    int e0 = fidx[t * 2], e1 = fidx[t * 2 + 1];
    float g0 = fga[t * 2], g1 = fga[t * 2 + 1];
    int p0 = finv[t * 2], p1 = finv[t * 2 + 1];
#pragma unroll
    for (int i = 0; i < 4; i++) {
        int d = tid + i * 256;
        out[(size_t)t * D + d] = x1[(size_t)t * D + d]
                               + g0 * b2[e0 * D + d] + g1 * b2[e1 * D + d]
                               + b2f(Of2b[(size_t)p0 * D + d]) + b2f(Of2b[(size_t)p1 * D + d]);
    }
}

extern "C" void kernel_launch(void* const* d_in, const int* in_sizes, int n_in,
                              void* d_out, int out_size, void* d_ws, size_t ws_size,
                              hipStream_t stream) {
    const float* src   = (const float*)d_in[0];
    const float* ln1_w = (const float*)d_in[1];
    const float* ln1_b = (const float*)d_in[2];
    const float* ln2_w = (const float*)d_in[3];
    const float* ln2_b = (const float*)d_in[4];
    const float* agw   = (const float*)d_in[5];
    const float* qw    = (const float*)d_in[6];
    const float* qb    = (const float*)d_in[7];
    const float* kw    = (const float*)d_in[8];
    const float* kb    = (const float*)d_in[9];
    const float* vw    = (const float*)d_in[10];
    const float* vb    = (const float*)d_in[11];
    const float* ow    = (const float*)d_in[12];
    const float* ob    = (const float*)d_in[13];
    const float* rel   = (const float*)d_in[14];
    const float* fgw   = (const float*)d_in[15];
    const float* w1    = (const float*)d_in[16];
    const float* b1    = (const float*)d_in[17];
    const float* w2    = (const float*)d_in[18];
    const float* b2    = (const float*)d_in[19];
    float* out = (float*)d_out;

    char* p = (char*)d_ws;
    float* xn1  = (float*)p; p += (size_t)NTOK * D * 4;               // LN out fp32 (router)
    float* x1   = (float*)p; p += (size_t)NTOK * D * 4;
    char*  sreg = p;         p += (size_t)NPAD * SEQ * 4;             // 34.1 MB
    float*  Sbuf = (float*)sreg;                                      // attn: scores (fp32) / P (bf16 in place)
    ushort* Pb   = (ushort*)sreg;                                     // bf16 P, row stride PROW
    ushort* Ofb  = (ushort*)sreg;                                     // attn: o rows (17 MB)
    ushort* w1t  = (ushort*)sreg;                                     // FFN: 16.78 MB
    ushort* w2t  = (ushort*)(sreg + (size_t)16777216);                // FFN: 16.78 MB
    char*  reg  = p;         p += (size_t)NPAD * 128 * 6 + (size_t)NPAIR * RSTRIDE * 4;
    ushort* ctx16 = (ushort*)reg;                                     // 2.13 MB (bf16 ctx)
    ushort* Qg   = (ushort*)(reg + (size_t)NPAD * 128 * 4);           // 2.13 MB
    float*  Rbuf = (float*)(reg + (size_t)NPAD * 128 * 6);            // 4.33 MB
    ushort* Hb   = (ushort*)reg;                                      // FFN hidden (8.52 MB)
    char*  arena = p;        p += (size_t)4 * NPAD * 128 * 4;         // 17.04 MB
    float*  kpart = (float*)arena;
    float*  vpart = (float*)(arena + (size_t)4 * NTOK * HD * 4);
    float*  qpart = (float*)arena;
    float*  ppart = (float*)arena;
    ushort* Of2b  = (ushort*)arena;
    ushort* kb16 = (ushort*)p; p += (size_t)NTOK * HD * 2;
    float* vbf  = (float*)p; p += (size_t)NTOK * HD * 4;
    ushort* vt16 = (ushort*)p; p += (size_t)NTOK * HD * 2;
    ushort* kwt = (ushort*)p; p += (size_t)HD * D * 2;
    ushort* vwt = (ushort*)p; p += (size_t)HD * D * 2;
    ushort* qwt = (ushort*)p; p += (size_t)EA * HD * D * 2;
    ushort* owt = (ushort*)p; p += (size_t)EA * D * HD * 2;
    ushort* relb = (ushort*)p; p += (size_t)RNUM * HD * 2 + 256;
    int*   aidx = (int*)p;   p += NPAIR * 4;
    float* aga  = (float*)p; p += NPAIR * 4;
    int*   fidx = (int*)p;   p += NPAIR * 4;
    float* fga  = (float*)p; p += NPAIR * 4;
    int*   ameta = (int*)p;  p += 128 * 4;
    int*   alist = (int*)p;  p += NPAIR * 4;
    int*   ainv = (int*)p;   p += NPAIR * 4;
    int*   fmeta = (int*)p;  p += 64 * 4;
    int*   flist = (int*)p;  p += NPAIR * 4;
    int*   finv = (int*)p;   p += NPAIR * 4;
    ushort* xnb = (ushort*)p; p += (size_t)NTOK * D * 2;              // bf16 LN out (GEMM A operand)
    float* xn2 = xn1;

    // ---- attention ----
    zero_meta<<<1, 128, 0, stream>>>(ameta, fmeta);
    ln_kernel<<<NTOK, 256, 0, stream>>>(src, ln1_w, ln1_b, xn1, xnb);
    router_kernel<EA><<<NTOK, 64, 0, stream>>>(xn1, agw, aidx, aga);
    abin_count<<<NPAIR / 256, 256, 0, stream>>>(aidx, ameta);
    abin_scan<<<1, 64, 0, stream>>>(ameta);
    abin_scatter<<<NPAIR / 256, 256, 0, stream>>>(aidx, ameta, alist, ainv);
    convT_kernel<1024, 128><<<dim3(32, 4, 1), 256, 0, stream>>>(kw, kwt);
    convT_kernel<1024, 128><<<dim3(32, 4, 1), 256, 0, stream>>>(vw, vwt);
    convT_kernel<1024, 128><<<dim3(32, 4, EA), 256, 0, stream>>>(qw, qwt);
    convT_kernel<128, 1024><<<dim3(4, 32, EA), 256, 0, stream>>>(ow, owt);
    conv_kernel<<<(RNUM * HD + 255) / 256, 256, 0, stream>>>(rel, relb, RNUM * HD);
    kv_mfma<<<dim3(64, 4, 2), 256, 0, stream>>>(xnb, kwt, vwt, kpart, vpart);
    kv_reduce<<<NTOK, 128, 0, stream>>>(kpart, vpart, kb, vb, kb16, vbf);
    convT_kernel<1024, 128><<<dim3(32, 4, 4), 256, 0, stream>>>(vbf, vt16);
    q_mfma<<<dim3(40, 4, EA), 256, 0, stream>>>(xnb, qwt, ameta, alist, qpart);
    q_reduce<<<NPAIR, 128, 0, stream>>>(qpart, qb, aidx, alist, Qg);
    rel_mfma<<<dim3(NPAIR / 64, 2), 256, 0, stream>>>(Qg, relb, Rbuf);
    s_mfma<<<dim3(12, 8, 32), 256, 0, stream>>>(Qg, kb16, Rbuf, ameta, alist, Sbuf);
    softmax_kernel<<<NPAIR, 256, 0, stream>>>(Sbuf);
    pv_mfma<<<dim3(12, 4, 32), 256, 0, stream>>>(Pb, vt16, ameta, ppart);
    pv_reduce<<<NPAIR, 128, 0, stream>>>(ppart, aga, alist, ctx16);
    o_mfma<<<dim3(40, 8, EA), 256, 0, stream>>>(ctx16, owt, ameta, Ofb);
    attn_combine<<<NTOK, 256, 0, stream>>>(src, ob, aidx, aga, ainv, Ofb, x1);

    // ---- FFN ----
    ln_kernel<<<NTOK, 256, 0, stream>>>(x1, ln2_w, ln2_b, xn2, xnb);
    router_kernel<EF><<<NTOK, 64, 0, stream>>>(xn2, fgw, fidx, fga);
    bin_count<<<NPAIR / 256, 256, 0, stream>>>(fidx, fmeta);
    bin_scan<<<1, 64, 0, stream>>>(fmeta);
    bin_scatter<<<NPAIR / 256, 256, 0, stream>>>(fidx, fmeta, flist, finv);
    convT_kernel<1024, 512><<<dim3(32, 16, EF), 256, 0, stream>>>(w1, w1t);
    convT_kernel<512, 1024><<<dim3(16, 32, EF), 256, 0, stream>>>(w2, w2t);
    ffn_mfma1<<<dim3(20, 4, EF), 256, 0, stream>>>(xnb, w1t, b1, fmeta, flist, fga, Hb);
    ffn_mfma2<<<dim3(20, 8, EF), 256, 0, stream>>>(Hb, w2t, fmeta, Of2b);
    ffn_combine<<<NTOK, 256, 0, stream>>>(x1, b2, fidx, fga, finv, Of2b, out);
}

// Round 7
// 493.770 us; speedup vs baseline: 1.0466x; 1.0124x over previous
//
#include <hip/hip_runtime.h>

#define D 1024
#define HD 128
#define EA 8
#define EF 16
#define FH 512
#define MAXPOS 64
#define RNUM 129
#define RSTRIDE 132
#define SEQ 1024
#define NTOK 4096
#define NPAIR (NTOK * 2)
#define NPAD 8320          // NPAIR + 128 slack
#define LN_EPS 1e-5f
#define QSCALE 0.08838834764831845f
#define BSTR 32            // linear LDS row stride in bf16 elems (global_load_lds needs linear)
#define PROW 2048          // bf16 P row stride in ushorts (= SEQ*4B slot)

typedef __attribute__((ext_vector_type(8))) short bf16x8;
typedef __attribute__((ext_vector_type(4))) float f32x4;
typedef __attribute__((ext_vector_type(8))) unsigned short u16x8;

__device__ inline ushort f2b(float f) {
    union { float f; unsigned u; } v; v.f = f;
    unsigned r = (v.u + 0x7fffu + ((v.u >> 16) & 1u)) >> 16;
    return (ushort)r;
}
__device__ inline float b2f(ushort u) {
    union { unsigned u; float f; } v; v.u = (unsigned)u << 16; return v.f;
}

// async global->LDS, 16B per lane, dest = wave-uniform base + lane*16
__device__ __forceinline__ void gll(const void* g, void* l) {
    __builtin_amdgcn_global_load_lds((const __attribute__((address_space(1))) void*)g,
                                     (__attribute__((address_space(3))) void*)l, 16, 0, 0);
}
__device__ __forceinline__ void wait_vm0() { asm volatile("s_waitcnt vmcnt(0)" ::: "memory"); }
__device__ __forceinline__ void wait_vm3() { asm volatile("s_waitcnt vmcnt(3)" ::: "memory"); }
__device__ __forceinline__ void bar() { __builtin_amdgcn_s_barrier(); }

// one double-buffer compute step: 64x128 tile, wave = 32x64
__device__ inline void mfma_step(const short* Asb, const short* Bsb,
                                 int wr, int wc, int m16, int q, f32x4 (&acc)[2][4]) {
    bf16x8 af[2], bfr[4];
#pragma unroll
    for (int i = 0; i < 2; i++) af[i] = *(const bf16x8*)&Asb[(wr + i * 16 + m16) * BSTR + q * 8];
#pragma unroll
    for (int j = 0; j < 4; j++) bfr[j] = *(const bf16x8*)&Bsb[(wc + j * 16 + m16) * BSTR + q * 8];
#pragma unroll
    for (int i = 0; i < 2; i++)
#pragma unroll
        for (int j = 0; j < 4; j++)
            acc[i][j] = __builtin_amdgcn_mfma_f32_16x16x32_bf16(af[i], bfr[j], acc[i][j], 0, 0, 0);
}

// depth-2 counted-vmcnt K-loop (T3/T4-lite).
#define KLOOP(NK, AP, BP0, BP1, STRIDE)                                          \
    gll(AP, &As[0][w * 512]); gll(BP0, &Bs[0][w * 1024]); gll(BP1, &Bs[0][w * 1024 + 512]); \
    gll(AP + STRIDE, &As[1][w * 512]); gll(BP0 + STRIDE, &Bs[1][w * 1024]);      \
    gll(BP1 + STRIDE, &Bs[1][w * 1024 + 512]);                                   \
    {                                                                            \
        int cur = 0;                                                             \
        for (int k = 0; k < NK; k++) {                                           \
            if (k < NK - 1) wait_vm3(); else wait_vm0();                         \
            bar();                                                               \
            mfma_step(As[cur], Bs[cur], wr, wc, m16, q, acc);                    \
            if (k + 2 < NK) {                                                    \
                bar();                                                           \
                gll(AP + (k + 2) * STRIDE, &As[cur][w * 512]);                   \
                gll(BP0 + (k + 2) * STRIDE, &Bs[cur][w * 1024]);                 \
                gll(BP1 + (k + 2) * STRIDE, &Bs[cur][w * 1024 + 512]);           \
            }                                                                    \
            cur ^= 1;                                                            \
        }                                                                        \
    }

// ---------------- LayerNorm (fp32 out for router + bf16 out for GEMMs) ----------------
__global__ void ln_kernel(const float* __restrict__ x, const float* __restrict__ w,
                          const float* __restrict__ b, float* __restrict__ y,
                          ushort* __restrict__ yb) {
    int row = blockIdx.x;
    const float* xr = x + (size_t)row * D;
    float v[4];
    float s = 0.f, s2 = 0.f;
#pragma unroll
    for (int i = 0; i < 4; i++) {
        v[i] = xr[threadIdx.x + i * 256];
        s += v[i]; s2 += v[i] * v[i];
    }
#pragma unroll
    for (int off = 32; off; off >>= 1) { s += __shfl_down(s, off); s2 += __shfl_down(s2, off); }
    __shared__ float red0[4], red1[4];
    int wave = threadIdx.x >> 6, lane = threadIdx.x & 63;
    if (lane == 0) { red0[wave] = s; red1[wave] = s2; }
    __syncthreads();
    float ts = red0[0] + red0[1] + red0[2] + red0[3];
    float ts2 = red1[0] + red1[1] + red1[2] + red1[3];
    float mu = ts * (1.f / D);
    float var = ts2 * (1.f / D) - mu * mu;
    float inv = rsqrtf(var + LN_EPS);
#pragma unroll
    for (int i = 0; i < 4; i++) {
        int d = threadIdx.x + i * 256;
        float o = (v[i] - mu) * inv * w[d] + b[d];
        y[(size_t)row * D + d] = o;
        yb[(size_t)row * D + d] = f2b(o);
    }
}

// ---------------- Router ----------------
template <int E>
__global__ void router_kernel(const float* __restrict__ xn, const float* __restrict__ gw,
                              int* __restrict__ idx, float* __restrict__ gate) {
    int t = blockIdx.x;
    int lane = threadIdx.x;  // block=64
    float acc[E];
#pragma unroll
    for (int e = 0; e < E; e++) acc[e] = 0.f;
    const float* xr = xn + (size_t)t * D;
    for (int d = lane; d < D; d += 64) {
        float xv = xr[d];
#pragma unroll
        for (int e = 0; e < E; e++) acc[e] += xv * gw[d * E + e];
    }
#pragma unroll
    for (int e = 0; e < E; e++) {
#pragma unroll
        for (int off = 32; off; off >>= 1) acc[e] += __shfl_down(acc[e], off);
    }
    if (lane == 0) {
        float v0 = -1e30f, v1 = -1e30f;
        int i0 = 0, i1 = 0;
#pragma unroll
        for (int e = 0; e < E; e++) {
            float a = acc[e];
            if (a > v0) { v1 = v0; i1 = i0; v0 = a; i0 = e; }
            else if (a > v1) { v1 = a; i1 = e; }
        }
        float g0 = 1.f / (1.f + expf(v1 - v0));
        idx[t * 2] = i0; idx[t * 2 + 1] = i1;
        gate[t * 2] = g0; gate[t * 2 + 1] = 1.f - g0;
    }
}

// ---------------- meta zeroing (attn + ffn merged) ----------------
__global__ void zero_meta(int* __restrict__ ameta, int* __restrict__ fmeta) {
    if (threadIdx.x < 105) ameta[threadIdx.x] = 0;
    if (threadIdx.x < 48) fmeta[threadIdx.x] = 0;
}

// ---------------- Attention binning: 32 bins keyed (expert*4 + batch) ----------------
__global__ void abin_count(const int* __restrict__ aidx, int* __restrict__ meta) {
    int i = blockIdx.x * 256 + threadIdx.x;
    if (i < NPAIR) {
        int e = aidx[i];
        int b = (i >> 1) >> 10;
        atomicAdd(&meta[e * 4 + b], 1);
    }
}
__global__ void abin_scan(int* __restrict__ meta) {
    if (threadIdx.x == 0 && blockIdx.x == 0) {
        int s = 0;
        for (int bin = 0; bin < 32; bin++) {
            if ((bin & 3) == 0) meta[96 + (bin >> 2)] = s;
            meta[32 + bin] = s; meta[64 + bin] = s; s += meta[bin];
        }
        meta[96 + 8] = s;
    }
}
__global__ void abin_scatter(const int* __restrict__ aidx, int* __restrict__ meta,
                             int* __restrict__ list, int* __restrict__ inv) {
    int i = blockIdx.x * 256 + threadIdx.x;
    if (i < NPAIR) {
        int e = aidx[i];
        int b = (i >> 1) >> 10;
        int pos = atomicAdd(&meta[64 + e * 4 + b], 1);
        list[pos] = i;
        inv[i] = pos;
    }
}

// ---------------- FFN binning ----------------
__global__ void bin_count(const int* __restrict__ fidx, int* __restrict__ meta) {
    int i = blockIdx.x * 256 + threadIdx.x;
    if (i < NPAIR) atomicAdd(&meta[fidx[i]], 1);
}
__global__ void bin_scan(int* __restrict__ meta) {
    if (threadIdx.x == 0 && blockIdx.x == 0) {
        int s = 0;
        for (int e = 0; e < EF; e++) { meta[16 + e] = s; meta[32 + e] = s; s += meta[e]; }
    }
}
__global__ void bin_scatter(const int* __restrict__ fidx, int* __restrict__ meta,
                            int* __restrict__ list, int* __restrict__ inv) {
    int i = blockIdx.x * 256 + threadIdx.x;
    if (i < NPAIR) {
        int e = fidx[i];
        int pos = atomicAdd(&meta[32 + e], 1);
        list[pos] = i;
        inv[i] = pos;
    }
}

// ---------------- transpose-convert [E][R][C] fp32 -> [E][C][R] bf16 ----------------
template <int R, int C>
__device__ __forceinline__ void convT_body(const float* __restrict__ src, ushort* __restrict__ dst) {
    int r0 = blockIdx.x * 32, c0 = blockIdx.y * 32;
    __shared__ float tile[32][33];
    int tx = threadIdx.x & 31, ty = threadIdx.x >> 5;  // 256 thr
#pragma unroll
    for (int i = 0; i < 32; i += 8)
        tile[ty + i][tx] = src[(size_t)(r0 + ty + i) * C + c0 + tx];
    __syncthreads();
#pragma unroll
    for (int i = 0; i < 32; i += 8)
        dst[(size_t)(c0 + ty + i) * R + r0 + tx] = f2b(tile[tx][ty + i]);
}
template <int R, int C>
__global__ void convT_kernel(const float* __restrict__ in, ushort* __restrict__ out) {
    int e = blockIdx.z;
    convT_body<R, C>(in + (size_t)e * R * C, out + (size_t)e * C * R);
}
__global__ void convT_kv(const float* __restrict__ kw, const float* __restrict__ vw,
                         ushort* __restrict__ kwt, ushort* __restrict__ vwt) {
    if (blockIdx.z == 0) convT_body<1024, 128>(kw, kwt);
    else                 convT_body<1024, 128>(vw, vwt);
}

// elementwise fp32 -> bf16 (small arrays)
__global__ void conv_kernel(const float* __restrict__ in, ushort* __restrict__ out, int n) {
    int i = blockIdx.x * 256 + threadIdx.x;
    if (i < n) out[i] = f2b(in[i]);
}

// ---------------- kv: split-K MFMA, dense per-split partials ----------------
__global__ __launch_bounds__(256) void kv_mfma(
    const ushort* __restrict__ xnb, const ushort* __restrict__ kwt,
    const ushort* __restrict__ vwt, float* __restrict__ kpart, float* __restrict__ vpart) {
    const ushort* W = blockIdx.z ? vwt : kwt;
    float* outp = blockIdx.z ? vpart : kpart;
    int m0 = blockIdx.x * 64;
    int s = blockIdx.y;
    int kbase = s * 256;
    __shared__ __align__(16) short As[2][64 * BSTR];
    __shared__ __align__(16) short Bs[2][128 * BSTR];
    int tid = threadIdx.x, w = tid >> 6, lane = tid & 63;
    int sr = lane >> 2, sc = (lane & 3) * 8;
    const ushort* ap = xnb + (size_t)(m0 + w * 16 + sr) * D + kbase + sc;
    const ushort* bp0 = W + (size_t)(w * 32 + sr) * D + kbase + sc;
    const ushort* bp1 = bp0 + (size_t)16 * D;
    int wr = (w >> 1) * 32, wc = (w & 1) * 64;
    int m16 = lane & 15, q = lane >> 4;
    f32x4 acc[2][4] = {};
    KLOOP(8, ap, bp0, bp1, 32)
#pragma unroll
    for (int i = 0; i < 2; i++)
#pragma unroll
        for (int r = 0; r < 4; r++) {
            int m = m0 + wr + i * 16 + q * 4 + r;
#pragma unroll
            for (int j = 0; j < 4; j++)
                outp[((size_t)s * NTOK + m) * HD + wc + j * 16 + m16] = acc[i][j][r];
        }
}

__global__ void kv_reduce(const float* __restrict__ kpart, const float* __restrict__ vpart,
                          const float* __restrict__ kb, const float* __restrict__ vb,
                          ushort* __restrict__ kb16, float* __restrict__ vbf) {
    int t = blockIdx.x, h = threadIdx.x;  // 128
    float ka = kb[h], va = vb[h];
#pragma unroll
    for (int s = 0; s < 4; s++) {
        ka += kpart[((size_t)s * NTOK + t) * HD + h];
        va += vpart[((size_t)s * NTOK + t) * HD + h];
    }
    kb16[(size_t)t * HD + h] = f2b(ka);
    vbf[(size_t)t * HD + h] = va;
}

// ---------------- q: split-K MFMA, indirect A, dense partials ----------------
__global__ __launch_bounds__(256) void q_mfma(
    const ushort* __restrict__ xnb, const ushort* __restrict__ qwt,
    const int* __restrict__ meta, const int* __restrict__ list, float* __restrict__ qpart) {
    int e = blockIdx.z;
    int o = meta[96 + e], c = meta[97 + e] - o;
    int m0 = blockIdx.x * 64;
    if (m0 >= c) return;
    int s = blockIdx.y;
    int kbase = s * 256;
    __shared__ __align__(16) short As[2][64 * BSTR];
    __shared__ __align__(16) short Bs[2][128 * BSTR];
    int tid = threadIdx.x, w = tid >> 6, lane = tid & 63;
    int sr = lane >> 2, sc = (lane & 3) * 8;
    int ri = o + m0 + w * 16 + sr; if (ri > NPAIR - 1) ri = NPAIR - 1;
    const ushort* ap = xnb + (size_t)(list[ri] >> 1) * D + kbase + sc;
    const ushort* bp0 = qwt + (size_t)e * HD * D + (size_t)(w * 32 + sr) * D + kbase + sc;
    const ushort* bp1 = bp0 + (size_t)16 * D;
    int wr = (w >> 1) * 32, wc = (w & 1) * 64;
    int m16 = lane & 15, q = lane >> 4;
    f32x4 acc[2][4] = {};
    KLOOP(8, ap, bp0, bp1, 32)
#pragma unroll
    for (int i = 0; i < 2; i++)
#pragma unroll
        for (int r = 0; r < 4; r++) {
            int pos = o + m0 + wr + i * 16 + q * 4 + r;
            if (pos < o + c) {
#pragma unroll
                for (int j = 0; j < 4; j++)
                    qpart[((size_t)s * NPAD + pos) * HD + wc + j * 16 + m16] = acc[i][j][r];
            }
        }
}

__global__ void q_reduce(const float* __restrict__ qpart, const float* __restrict__ qb,
                         const int* __restrict__ aidx, const int* __restrict__ list,
                         ushort* __restrict__ Qg) {
    int pos = blockIdx.x, h = threadIdx.x;  // 128
    int e = aidx[list[pos]];
    float a = qb[e * HD + h];
#pragma unroll
    for (int s = 0; s < 4; s++) a += qpart[((size_t)s * NPAD + pos) * HD + h];
    Qg[(size_t)pos * HD + h] = f2b(a * QSCALE);
}

// ---------------- rel: MFMA GEMM  R[pos][r] = Qg[pos] . rel[r] ----------------
__global__ __launch_bounds__(256) void rel_mfma(
    const ushort* __restrict__ Qg, const ushort* __restrict__ relb,
    float* __restrict__ R) {
    int m0 = blockIdx.x * 64;
    int n0 = blockIdx.y * 128;
    __shared__ __align__(16) short As[2][64 * BSTR];
    __shared__ __align__(16) short Bs[2][128 * BSTR];
    int tid = threadIdx.x, w = tid >> 6, lane = tid & 63;
    int sr = lane >> 2, sc = (lane & 3) * 8;
    const ushort* ap = Qg + (size_t)(m0 + w * 16 + sr) * HD + sc;
    int r0 = n0 + w * 32 + sr;      if (r0 > RNUM - 1) r0 = RNUM - 1;
    int r1 = n0 + w * 32 + 16 + sr; if (r1 > RNUM - 1) r1 = RNUM - 1;
    const ushort* bp0 = relb + (size_t)r0 * HD + sc;
    const ushort* bp1 = relb + (size_t)r1 * HD + sc;
    int wr = (w >> 1) * 32, wc = (w & 1) * 64;
    int m16 = lane & 15, q = lane >> 4;
    f32x4 acc[2][4] = {};
    KLOOP(4, ap, bp0, bp1, 32)
#pragma unroll
    for (int i = 0; i < 2; i++)
#pragma unroll
        for (int r = 0; r < 4; r++) {
            int pos = m0 + wr + i * 16 + q * 4 + r;
#pragma unroll
            for (int j = 0; j < 4; j++) {
                int n = n0 + wc + j * 16 + m16;
                if (n < RNUM) R[(size_t)pos * RSTRIDE + n] = acc[i][j][r];
            }
        }
}

// ---------------- s: MFMA QK^T + rel bias, fp32 S out (B staged from bf16 kb16) -------
__global__ __launch_bounds__(256) void s_mfma(
    const ushort* __restrict__ Qg, const ushort* __restrict__ kb16,
    const float* __restrict__ R, const int* __restrict__ meta,
    const int* __restrict__ list, float* __restrict__ S) {
    int bin = blockIdx.z;
    int o = meta[32 + bin], c = meta[bin];
    int m0 = blockIdx.x * 64;
    if (m0 >= c) return;
    int b = bin & 3;
    int n0 = blockIdx.y * 128;
    __shared__ __align__(16) short As[2][64 * BSTR];
    __shared__ __align__(16) short Bs[2][128 * BSTR];
    int tid = threadIdx.x, w = tid >> 6, lane = tid & 63;
    int sr = lane >> 2, sc = (lane & 3) * 8;
    int ar = o + m0 + w * 16 + sr; if (ar > NPAIR - 1) ar = NPAIR - 1;   // poison guard
    const ushort* ap = Qg + (size_t)ar * HD + sc;
    const ushort* bp0 = kb16 + ((size_t)b * SEQ + n0 + w * 32 + sr) * HD + sc;
    const ushort* bp1 = bp0 + (size_t)16 * HD;
    int wr = (w >> 1) * 32, wc = (w & 1) * 64;
    int m16 = lane & 15, q = lane >> 4;
    f32x4 acc[2][4] = {};
    KLOOP(4, ap, bp0, bp1, 32)
#pragma unroll
    for (int i = 0; i < 2; i++)
#pragma unroll
        for (int r = 0; r < 4; r++) {
            int pos = o + m0 + wr + i * 16 + q * 4 + r;
            if (pos < o + c) {
                int qpos = (list[pos] >> 1) & (SEQ - 1);
                const float* Rrow = R + (size_t)pos * RSTRIDE;
                float* sr_ = S + (size_t)pos * SEQ;
#pragma unroll
                for (int j = 0; j < 4; j++) {
                    int key = n0 + wc + j * 16 + m16;
                    int rix = key - qpos;
                    rix = (rix < -MAXPOS ? -MAXPOS : (rix > MAXPOS ? MAXPOS : rix)) + MAXPOS;
                    sr_[key] = acc[i][j][r] + Rrow[rix];
                }
            }
        }
}

// ---------------- Row softmax: fp32 S in, bf16 P out (in place, same row slot) ----------------
__global__ __launch_bounds__(256) void softmax_kernel(float* __restrict__ S) {
    int row = blockIdx.x;
    float4* sr = (float4*)(S + (size_t)row * SEQ);
    float4 v = sr[threadIdx.x];
    float m = fmaxf(fmaxf(v.x, v.y), fmaxf(v.z, v.w));
#pragma unroll
    for (int off = 32; off; off >>= 1) m = fmaxf(m, __shfl_down(m, off));
    __shared__ float red0[4], red1[4];
    int wave = threadIdx.x >> 6, lane = threadIdx.x & 63;
    if (lane == 0) red0[wave] = m;
    __syncthreads();
    m = fmaxf(fmaxf(red0[0], red0[1]), fmaxf(red0[2], red0[3]));
    v.x = __expf(v.x - m); v.y = __expf(v.y - m);
    v.z = __expf(v.z - m); v.w = __expf(v.w - m);
    float s = v.x + v.y + v.z + v.w;
#pragma unroll
    for (int off = 32; off; off >>= 1) s += __shfl_down(s, off);
    if (lane == 0) red1[wave] = s;
    __syncthreads();
    float inv = 1.f / (red1[0] + red1[1] + red1[2] + red1[3]);
    // all reads of this row completed before the preceding barrier; safe in-place bf16 write
    ushort* pr = (ushort*)(S + (size_t)row * SEQ);
    ushort4 p4 = { f2b(v.x * inv), f2b(v.y * inv), f2b(v.z * inv), f2b(v.w * inv) };
    *(ushort4*)(pr + threadIdx.x * 4) = p4;
}

// ---------------- pv: split-K MFMA P@V (bf16 P direct), dense partials ----------------
__global__ __launch_bounds__(256) void pv_mfma(
    const ushort* __restrict__ Pb, const ushort* __restrict__ vt16,
    const int* __restrict__ meta, float* __restrict__ ppart) {
    int bin = blockIdx.z;
    int o = meta[32 + bin], c = meta[bin];
    int m0 = blockIdx.x * 64;
    if (m0 >= c) return;
    int b = bin & 3;
    int s = blockIdx.y;
    int kbase = s * 256;
    __shared__ __align__(16) short As[2][64 * BSTR];
    __shared__ __align__(16) short Bs[2][128 * BSTR];
    int tid = threadIdx.x, w = tid >> 6, lane = tid & 63;
    int sr = lane >> 2, sc = (lane & 3) * 8;
    int ar = o + m0 + w * 16 + sr; if (ar > NPAIR - 1) ar = NPAIR - 1;   // poison guard
    const ushort* ap = Pb + (size_t)ar * PROW + kbase + sc;
    const ushort* bp0 = vt16 + (size_t)b * HD * SEQ + (size_t)(w * 32 + sr) * SEQ + kbase + sc;
    const ushort* bp1 = bp0 + (size_t)16 * SEQ;
    int wr = (w >> 1) * 32, wc = (w & 1) * 64;
    int m16 = lane & 15, q = lane >> 4;
    f32x4 acc[2][4] = {};
    KLOOP(8, ap, bp0, bp1, 32)
#pragma unroll
    for (int i = 0; i < 2; i++)
#pragma unroll
        for (int r = 0; r < 4; r++) {
            int pos = o + m0 + wr + i * 16 + q * 4 + r;
            if (pos < o + c) {
#pragma unroll
                for (int j = 0; j < 4; j++)
                    ppart[((size_t)s * NPAD + pos) * HD + wc + j * 16 + m16] = acc[i][j][r];
            }
        }
}

__global__ void pv_reduce(const float* __restrict__ ppart, const float* __restrict__ aga,
                          const int* __restrict__ list, ushort* __restrict__ ctx16) {
    int pos = blockIdx.x, h = threadIdx.x;  // 128
    float g = aga[list[pos]];
    float a = 0.f;
#pragma unroll
    for (int s = 0; s < 4; s++) a += ppart[((size_t)s * NPAD + pos) * HD + h];
    ctx16[(size_t)pos * HD + h] = f2b(a * g);
}

// ---------------- o: MFMA ctx@o_w, dense bf16 per-pair rows ----------------
__global__ __launch_bounds__(256) void o_mfma(
    const ushort* __restrict__ ctx16, const ushort* __restrict__ owt,
    const int* __restrict__ meta, ushort* __restrict__ Ofb) {
    int e = blockIdx.z;
    int o = meta[96 + e], c = meta[97 + e] - o;
    int m0 = blockIdx.x * 64;
    if (m0 >= c) return;
    int n0 = blockIdx.y * 128;
    __shared__ __align__(16) short As[2][64 * BSTR];
    __shared__ __align__(16) short Bs[2][128 * BSTR];
    int tid = threadIdx.x, w = tid >> 6, lane = tid & 63;
    int sr = lane >> 2, sc = (lane & 3) * 8;
    int ar = o + m0 + w * 16 + sr; if (ar > NPAIR - 1) ar = NPAIR - 1;   // poison guard
    const ushort* ap = ctx16 + (size_t)ar * HD + sc;
    const ushort* bp0 = owt + (size_t)e * D * HD + (size_t)(n0 + w * 32 + sr) * HD + sc;
    const ushort* bp1 = bp0 + (size_t)16 * HD;
    int wr = (w >> 1) * 32, wc = (w & 1) * 64;
    int m16 = lane & 15, q = lane >> 4;
    f32x4 acc[2][4] = {};
    KLOOP(4, ap, bp0, bp1, 32)
#pragma unroll
    for (int i = 0; i < 2; i++)
#pragma unroll
        for (int r = 0; r < 4; r++) {
            int pos = o + m0 + wr + i * 16 + q * 4 + r;
            if (pos < o + c) {
#pragma unroll
                for (int j = 0; j < 4; j++)
                    Ofb[(size_t)pos * D + n0 + wc + j * 16 + m16] = f2b(acc[i][j][r]);
            }
        }
}

// ---------------- attn combine ----------------
__global__ void attn_combine(const float* __restrict__ src, const float* __restrict__ ob,
                             const int* __restrict__ aidx, const float* __restrict__ aga,
                             const int* __restrict__ ainv, const ushort* __restrict__ Ofb,
                             float* __restrict__ x1) {
    int t = blockIdx.x, tid = threadIdx.x;
    int e0 = aidx[t * 2], e1 = aidx[t * 2 + 1];
    float g0 = aga[t * 2], g1 = aga[t * 2 + 1];
    int p0 = ainv[t * 2], p1 = ainv[t * 2 + 1];
#pragma unroll
    for (int i = 0; i < 4; i++) {
        int d = tid + i * 256;
        x1[(size_t)t * D + d] = src[(size_t)t * D + d]
                              + g0 * ob[e0 * D + d] + g1 * ob[e1 * D + d]
                              + b2f(Ofb[(size_t)p0 * D + d]) + b2f(Ofb[(size_t)p1 * D + d]);
    }
}

// ---------------- FFN GEMM1: Hb = g*relu(xn2 @ W1 + b1) ----------------
__global__ __launch_bounds__(256) void ffn_mfma1(
    const ushort* __restrict__ xnb2, const ushort* __restrict__ w1t,
    const float* __restrict__ b1, const int* __restrict__ meta,
    const int* __restrict__ list, const float* __restrict__ fga,
    ushort* __restrict__ Hb) {
    int e = blockIdx.z;
    int o = meta[16 + e], c = meta[e];
    int m0 = blockIdx.x * 64;
    if (m0 >= c) return;
    int n0 = blockIdx.y * 128;
    __shared__ __align__(16) short As[2][64 * BSTR];
    __shared__ __align__(16) short Bs[2][128 * BSTR];
    int tid = threadIdx.x, w = tid >> 6, lane = tid & 63;
    int sr = lane >> 2, sc = (lane & 3) * 8;
    int ri = o + m0 + w * 16 + sr; if (ri > NPAIR - 1) ri = NPAIR - 1;
    const ushort* ap = xnb2 + (size_t)(list[ri] >> 1) * D + sc;
    const ushort* bp0 = w1t + ((size_t)e * FH + n0 + w * 32 + sr) * D + sc;
    const ushort* bp1 = bp0 + (size_t)16 * D;
    int wr = (w >> 1) * 32, wc = (w & 1) * 64;
    int m16 = lane & 15, q = lane >> 4;
    f32x4 acc[2][4] = {};
    KLOOP(32, ap, bp0, bp1, 32)
#pragma unroll
    for (int i = 0; i < 2; i++)
#pragma unroll
        for (int r = 0; r < 4; r++) {
            int pos = o + m0 + wr + i * 16 + q * 4 + r;
            if (pos < o + c) {
                float g = fga[list[pos]];
#pragma unroll
                for (int j = 0; j < 4; j++) {
                    int n = n0 + wc + j * 16 + m16;
                    Hb[(size_t)pos * FH + n] = f2b(g * fmaxf(acc[i][j][r] + b1[e * FH + n], 0.f));
                }
            }
        }
}

// ---------------- FFN GEMM2: Of2b[pos] = Hb @ W2 (dense bf16 rows) ----------------
__global__ __launch_bounds__(256) void ffn_mfma2(
    const ushort* __restrict__ Hb, const ushort* __restrict__ w2t,
    const int* __restrict__ meta, ushort* __restrict__ Of2b) {
    int e = blockIdx.z;
    int o = meta[16 + e], c = meta[e];
    int m0 = blockIdx.x * 64;
    if (m0 >= c) return;
    int n0 = blockIdx.y * 128;
    __shared__ __align__(16) short As[2][64 * BSTR];
    __shared__ __align__(16) short Bs[2][128 * BSTR];
    int tid = threadIdx.x, w = tid >> 6, lane = tid & 63;
    int sr = lane >> 2, sc = (lane & 3) * 8;
    int ar = o + m0 + w * 16 + sr; if (ar > NPAIR - 1) ar = NPAIR - 1;   // poison guard
    const ushort* ap = Hb + (size_t)ar * FH + sc;
    const ushort* bp0 = w2t + ((size_t)e * D + n0 + w * 32 + sr) * FH + sc;
    const ushort* bp1 = bp0 + (size_t)16 * FH;
    int wr = (w >> 1) * 32, wc = (w & 1) * 64;
    int m16 = lane & 15, q = lane >> 4;
    f32x4 acc[2][4] = {};
    KLOOP(16, ap, bp0, bp1, 32)
#pragma unroll
    for (int i = 0; i < 2; i++)
#pragma unroll
        for (int r = 0; r < 4; r++) {
            int pos = o + m0 + wr + i * 16 + q * 4 + r;
            if (pos < o + c) {
#pragma unroll
                for (int j = 0; j < 4; j++)
                    Of2b[(size_t)pos * D + n0 + wc + j * 16 + m16] = f2b(acc[i][j][r]);
            }
        }
}

// ---------------- FFN combine ----------------
__global__ void ffn_combine(const float* __restrict__ x1, const float* __restrict__ b2,
                            const int* __restrict__ fidx, const float* __restrict__ fga,
                            const int* __restrict__ finv, const ushort* __restrict__ Of2b,
                            float* __restrict__ out) {
    int t = blockIdx.x, tid = threadIdx.x;
    int e0 = fidx[t * 2], e1 = fidx[t * 2 + 1];
    float g0 = fga[t * 2], g1 = fga[t * 2 + 1];
    int p0 = finv[t * 2], p1 = finv[t * 2 + 1];
#pragma unroll
    for (int i = 0; i < 4; i++) {
        int d = tid + i * 256;
        out[(size_t)t * D + d] = x1[(size_t)t * D + d]
                               + g0 * b2[e0 * D + d] + g1 * b2[e1 * D + d]
                               + b2f(Of2b[(size_t)p0 * D + d]) + b2f(Of2b[(size_t)p1 * D + d]);
    }
}

extern "C" void kernel_launch(void* const* d_in, const int* in_sizes, int n_in,
                              void* d_out, int out_size, void* d_ws, size_t ws_size,
                              hipStream_t stream) {
    const float* src   = (const float*)d_in[0];
    const float* ln1_w = (const float*)d_in[1];
    const float* ln1_b = (const float*)d_in[2];
    const float* ln2_w = (const float*)d_in[3];
    const float* ln2_b = (const float*)d_in[4];
    const float* agw   = (const float*)d_in[5];
    const float* qw    = (const float*)d_in[6];
    const float* qb    = (const float*)d_in[7];
    const float* kw    = (const float*)d_in[8];
    const float* kb    = (const float*)d_in[9];
    const float* vw    = (const float*)d_in[10];
    const float* vb    = (const float*)d_in[11];
    const float* ow    = (const float*)d_in[12];
    const float* ob    = (const float*)d_in[13];
    const float* rel   = (const float*)d_in[14];
    const float* fgw   = (const float*)d_in[15];
    const float* w1    = (const float*)d_in[16];
    const float* b1    = (const float*)d_in[17];
    const float* w2    = (const float*)d_in[18];
    const float* b2    = (const float*)d_in[19];
    float* out = (float*)d_out;

    char* p = (char*)d_ws;
    float* xn1  = (float*)p; p += (size_t)NTOK * D * 4;               // LN out fp32 (router)
    float* x1   = (float*)p; p += (size_t)NTOK * D * 4;
    char*  sreg = p;         p += (size_t)NPAD * SEQ * 4;             // 34.1 MB
    float*  Sbuf = (float*)sreg;                                      // attn: scores (fp32) / P (bf16 in place)
    ushort* Pb   = (ushort*)sreg;                                     // bf16 P, row stride PROW
    ushort* Ofb  = (ushort*)sreg;                                     // attn: o rows (17 MB)
    ushort* w1t  = (ushort*)sreg;                                     // FFN: 16.78 MB
    ushort* w2t  = (ushort*)(sreg + (size_t)16777216);                // FFN: 16.78 MB
    char*  reg  = p;         p += (size_t)NPAD * 128 * 6 + (size_t)NPAIR * RSTRIDE * 4;
    ushort* ctx16 = (ushort*)reg;                                     // bf16 ctx (2.13 MB slot)
    ushort* Qg   = (ushort*)(reg + (size_t)NPAD * 128 * 4);           // 2.13 MB
    float*  Rbuf = (float*)(reg + (size_t)NPAD * 128 * 6);            // 4.33 MB
    ushort* Hb   = (ushort*)reg;                                      // FFN hidden (8.52 MB)
    char*  arena = p;        p += (size_t)4 * NPAD * 128 * 4;         // 17.04 MB
    float*  kpart = (float*)arena;
    float*  vpart = (float*)(arena + (size_t)4 * NTOK * HD * 4);
    float*  qpart = (float*)arena;
    float*  ppart = (float*)arena;
    ushort* Of2b  = (ushort*)arena;
    ushort* kb16 = (ushort*)p; p += (size_t)NTOK * HD * 2;
    float* vbf  = (float*)p; p += (size_t)NTOK * HD * 4;
    ushort* vt16 = (ushort*)p; p += (size_t)NTOK * HD * 2;
    ushort* kwt = (ushort*)p; p += (size_t)HD * D * 2;
    ushort* vwt = (ushort*)p; p += (size_t)HD * D * 2;
    ushort* qwt = (ushort*)p; p += (size_t)EA * HD * D * 2;
    ushort* owt = (ushort*)p; p += (size_t)EA * D * HD * 2;
    ushort* relb = (ushort*)p; p += (size_t)RNUM * HD * 2 + 256;
    int*   aidx = (int*)p;   p += NPAIR * 4;
    float* aga  = (float*)p; p += NPAIR * 4;
    int*   fidx = (int*)p;   p += NPAIR * 4;
    float* fga  = (float*)p; p += NPAIR * 4;
    int*   ameta = (int*)p;  p += 128 * 4;
    int*   alist = (int*)p;  p += NPAIR * 4;
    int*   ainv = (int*)p;   p += NPAIR * 4;
    int*   fmeta = (int*)p;  p += 64 * 4;
    int*   flist = (int*)p;  p += NPAIR * 4;
    int*   finv = (int*)p;   p += NPAIR * 4;
    ushort* xnb = (ushort*)p; p += (size_t)NTOK * D * 2;              // bf16 LN out (GEMM A operand)
    float* xn2 = xn1;

    // ---- attention ----
    zero_meta<<<1, 128, 0, stream>>>(ameta, fmeta);
    ln_kernel<<<NTOK, 256, 0, stream>>>(src, ln1_w, ln1_b, xn1, xnb);
    router_kernel<EA><<<NTOK, 64, 0, stream>>>(xn1, agw, aidx, aga);
    abin_count<<<NPAIR / 256, 256, 0, stream>>>(aidx, ameta);
    abin_scan<<<1, 64, 0, stream>>>(ameta);
    abin_scatter<<<NPAIR / 256, 256, 0, stream>>>(aidx, ameta, alist, ainv);
    convT_kv<<<dim3(32, 4, 2), 256, 0, stream>>>(kw, vw, kwt, vwt);
    convT_kernel<1024, 128><<<dim3(32, 4, EA), 256, 0, stream>>>(qw, qwt);
    convT_kernel<128, 1024><<<dim3(4, 32, EA), 256, 0, stream>>>(ow, owt);
    conv_kernel<<<(RNUM * HD + 255) / 256, 256, 0, stream>>>(rel, relb, RNUM * HD);
    kv_mfma<<<dim3(64, 4, 2), 256, 0, stream>>>(xnb, kwt, vwt, kpart, vpart);
    kv_reduce<<<NTOK, 128, 0, stream>>>(kpart, vpart, kb, vb, kb16, vbf);
    convT_kernel<1024, 128><<<dim3(32, 4, 4), 256, 0, stream>>>(vbf, vt16);
    q_mfma<<<dim3(40, 4, EA), 256, 0, stream>>>(xnb, qwt, ameta, alist, qpart);
    q_reduce<<<NPAIR, 128, 0, stream>>>(qpart, qb, aidx, alist, Qg);
    rel_mfma<<<dim3(NPAIR / 64, 2), 256, 0, stream>>>(Qg, relb, Rbuf);
    s_mfma<<<dim3(12, 8, 32), 256, 0, stream>>>(Qg, kb16, Rbuf, ameta, alist, Sbuf);
    softmax_kernel<<<NPAIR, 256, 0, stream>>>(Sbuf);
    pv_mfma<<<dim3(12, 4, 32), 256, 0, stream>>>(Pb, vt16, ameta, ppart);
    pv_reduce<<<NPAIR, 128, 0, stream>>>(ppart, aga, alist, ctx16);
    o_mfma<<<dim3(40, 8, EA), 256, 0, stream>>>(ctx16, owt, ameta, Ofb);
    attn_combine<<<NTOK, 256, 0, stream>>>(src, ob, aidx, aga, ainv, Ofb, x1);

    // ---- FFN ----
    ln_kernel<<<NTOK, 256, 0, stream>>>(x1, ln2_w, ln2_b, xn2, xnb);
    router_kernel<EF><<<NTOK, 64, 0, stream>>>(xn2, fgw, fidx, fga);
    bin_count<<<NPAIR / 256, 256, 0, stream>>>(fidx, fmeta);
    bin_scan<<<1, 64, 0, stream>>>(fmeta);
    bin_scatter<<<NPAIR / 256, 256, 0, stream>>>(fidx, fmeta, flist, finv);
    convT_kernel<1024, 512><<<dim3(32, 16, EF), 256, 0, stream>>>(w1, w1t);
    convT_kernel<512, 1024><<<dim3(16, 32, EF), 256, 0, stream>>>(w2, w2t);
    ffn_mfma1<<<dim3(20, 4, EF), 256, 0, stream>>>(xnb, w1t, b1, fmeta, flist, fga, Hb);
    ffn_mfma2<<<dim3(20, 8, EF), 256, 0, stream>>>(Hb, w2t, fmeta, Of2b);
    ffn_combine<<<NTOK, 256, 0, stream>>>(x1, b2, fidx, fga, finv, Of2b, out);
}

// Round 9
// 492.500 us; speedup vs baseline: 1.0493x; 1.0026x over previous
//
#include <hip/hip_runtime.h>

#define D 1024
#define HD 128
#define EA 8
#define EF 16
#define FH 512
#define MAXPOS 64
#define RNUM 129
#define RSTRIDE 132
#define SEQ 1024
#define NTOK 4096
#define NPAIR (NTOK * 2)
#define NPAD 8320          // NPAIR + 128 slack
#define LN_EPS 1e-5f
#define QSCALE 0.08838834764831845f
#define BSTR 32            // linear LDS row stride in bf16 elems (global_load_lds needs linear)
#define PROW 2048          // bf16 P row stride in ushorts (= SEQ*4B slot)
#define NSPL 2             // split-K splits (green structure, halved traffic vs 4)

typedef __attribute__((ext_vector_type(8))) short bf16x8;
typedef __attribute__((ext_vector_type(4))) float f32x4;
typedef __attribute__((ext_vector_type(8))) unsigned short u16x8;

__device__ inline ushort f2b(float f) {
    union { float f; unsigned u; } v; v.f = f;
    unsigned r = (v.u + 0x7fffu + ((v.u >> 16) & 1u)) >> 16;
    return (ushort)r;
}
__device__ inline float b2f(ushort u) {
    union { unsigned u; float f; } v; v.u = (unsigned)u << 16; return v.f;
}

// async global->LDS, 16B per lane, dest = wave-uniform base + lane*16
__device__ __forceinline__ void gll(const void* g, void* l) {
    __builtin_amdgcn_global_load_lds((const __attribute__((address_space(1))) void*)g,
                                     (__attribute__((address_space(3))) void*)l, 16, 0, 0);
}
__device__ __forceinline__ void wait_vm0() { asm volatile("s_waitcnt vmcnt(0)" ::: "memory"); }
__device__ __forceinline__ void wait_vm3() { asm volatile("s_waitcnt vmcnt(3)" ::: "memory"); }
__device__ __forceinline__ void bar() { __builtin_amdgcn_s_barrier(); }

// one double-buffer compute step: 64x128 tile, wave = 32x64
__device__ inline void mfma_step(const short* Asb, const short* Bsb,
                                 int wr, int wc, int m16, int q, f32x4 (&acc)[2][4]) {
    bf16x8 af[2], bfr[4];
#pragma unroll
    for (int i = 0; i < 2; i++) af[i] = *(const bf16x8*)&Asb[(wr + i * 16 + m16) * BSTR + q * 8];
#pragma unroll
    for (int j = 0; j < 4; j++) bfr[j] = *(const bf16x8*)&Bsb[(wc + j * 16 + m16) * BSTR + q * 8];
#pragma unroll
    for (int i = 0; i < 2; i++)
#pragma unroll
        for (int j = 0; j < 4; j++)
            acc[i][j] = __builtin_amdgcn_mfma_f32_16x16x32_bf16(af[i], bfr[j], acc[i][j], 0, 0, 0);
}

// depth-2 counted-vmcnt K-loop (T3/T4-lite).
#define KLOOP(NK, AP, BP0, BP1, STRIDE)                                          \
    gll(AP, &As[0][w * 512]); gll(BP0, &Bs[0][w * 1024]); gll(BP1, &Bs[0][w * 1024 + 512]); \
    gll(AP + STRIDE, &As[1][w * 512]); gll(BP0 + STRIDE, &Bs[1][w * 1024]);      \
    gll(BP1 + STRIDE, &Bs[1][w * 1024 + 512]);                                   \
    {                                                                            \
        int cur = 0;                                                             \
        for (int k = 0; k < NK; k++) {                                           \
            if (k < NK - 1) wait_vm3(); else wait_vm0();                         \
            bar();                                                               \
            mfma_step(As[cur], Bs[cur], wr, wc, m16, q, acc);                    \
            if (k + 2 < NK) {                                                    \
                bar();                                                           \
                gll(AP + (k + 2) * STRIDE, &As[cur][w * 512]);                   \
                gll(BP0 + (k + 2) * STRIDE, &Bs[cur][w * 1024]);                 \
                gll(BP1 + (k + 2) * STRIDE, &Bs[cur][w * 1024 + 512]);           \
            }                                                                    \
            cur ^= 1;                                                            \
        }                                                                        \
    }

// ---------------- LayerNorm (fp32 out for router + bf16 out for GEMMs) ----------------
__global__ void ln_kernel(const float* __restrict__ x, const float* __restrict__ w,
                          const float* __restrict__ b, float* __restrict__ y,
                          ushort* __restrict__ yb) {
    int row = blockIdx.x;
    const float* xr = x + (size_t)row * D;
    float v[4];
    float s = 0.f, s2 = 0.f;
#pragma unroll
    for (int i = 0; i < 4; i++) {
        v[i] = xr[threadIdx.x + i * 256];
        s += v[i]; s2 += v[i] * v[i];
    }
#pragma unroll
    for (int off = 32; off; off >>= 1) { s += __shfl_down(s, off); s2 += __shfl_down(s2, off); }
    __shared__ float red0[4], red1[4];
    int wave = threadIdx.x >> 6, lane = threadIdx.x & 63;
    if (lane == 0) { red0[wave] = s; red1[wave] = s2; }
    __syncthreads();
    float ts = red0[0] + red0[1] + red0[2] + red0[3];
    float ts2 = red1[0] + red1[1] + red1[2] + red1[3];
    float mu = ts * (1.f / D);
    float var = ts2 * (1.f / D) - mu * mu;
    float inv = rsqrtf(var + LN_EPS);
#pragma unroll
    for (int i = 0; i < 4; i++) {
        int d = threadIdx.x + i * 256;
        float o = (v[i] - mu) * inv * w[d] + b[d];
        y[(size_t)row * D + d] = o;
        yb[(size_t)row * D + d] = f2b(o);
    }
}

// ---------------- Router ----------------
template <int E>
__global__ void router_kernel(const float* __restrict__ xn, const float* __restrict__ gw,
                              int* __restrict__ idx, float* __restrict__ gate) {
    int t = blockIdx.x;
    int lane = threadIdx.x;  // block=64
    float acc[E];
#pragma unroll
    for (int e = 0; e < E; e++) acc[e] = 0.f;
    const float* xr = xn + (size_t)t * D;
    for (int d = lane; d < D; d += 64) {
        float xv = xr[d];
#pragma unroll
        for (int e = 0; e < E; e++) acc[e] += xv * gw[d * E + e];
    }
#pragma unroll
    for (int e = 0; e < E; e++) {
#pragma unroll
        for (int off = 32; off; off >>= 1) acc[e] += __shfl_down(acc[e], off);
    }
    if (lane == 0) {
        float v0 = -1e30f, v1 = -1e30f;
        int i0 = 0, i1 = 0;
#pragma unroll
        for (int e = 0; e < E; e++) {
            float a = acc[e];
            if (a > v0) { v1 = v0; i1 = i0; v0 = a; i0 = e; }
            else if (a > v1) { v1 = a; i1 = e; }
        }
        float g0 = 1.f / (1.f + expf(v1 - v0));
        idx[t * 2] = i0; idx[t * 2 + 1] = i1;
        gate[t * 2] = g0; gate[t * 2 + 1] = 1.f - g0;
    }
}

// ---------------- meta zeroing (attn + ffn merged) ----------------
__global__ void zero_meta(int* __restrict__ ameta, int* __restrict__ fmeta) {
    if (threadIdx.x < 105) ameta[threadIdx.x] = 0;
    if (threadIdx.x < 48) fmeta[threadIdx.x] = 0;
}

// ---------------- Attention binning: 32 bins keyed (expert*4 + batch) ----------------
__global__ void abin_count(const int* __restrict__ aidx, int* __restrict__ meta) {
    int i = blockIdx.x * 256 + threadIdx.x;
    if (i < NPAIR) {
        int e = aidx[i];
        int b = (i >> 1) >> 10;
        atomicAdd(&meta[e * 4 + b], 1);
    }
}
__global__ void abin_scan(int* __restrict__ meta) {
    if (threadIdx.x == 0 && blockIdx.x == 0) {
        int s = 0;
        for (int bin = 0; bin < 32; bin++) {
            if ((bin & 3) == 0) meta[96 + (bin >> 2)] = s;
            meta[32 + bin] = s; meta[64 + bin] = s; s += meta[bin];
        }
        meta[96 + 8] = s;
    }
}
__global__ void abin_scatter(const int* __restrict__ aidx, int* __restrict__ meta,
                             int* __restrict__ list, int* __restrict__ inv) {
    int i = blockIdx.x * 256 + threadIdx.x;
    if (i < NPAIR) {
        int e = aidx[i];
        int b = (i >> 1) >> 10;
        int pos = atomicAdd(&meta[64 + e * 4 + b], 1);
        list[pos] = i;
        inv[i] = pos;
    }
}

// ---------------- FFN binning ----------------
__global__ void bin_count(const int* __restrict__ fidx, int* __restrict__ meta) {
    int i = blockIdx.x * 256 + threadIdx.x;
    if (i < NPAIR) atomicAdd(&meta[fidx[i]], 1);
}
__global__ void bin_scan(int* __restrict__ meta) {
    if (threadIdx.x == 0 && blockIdx.x == 0) {
        int s = 0;
        for (int e = 0; e < EF; e++) { meta[16 + e] = s; meta[32 + e] = s; s += meta[e]; }
    }
}
__global__ void bin_scatter(const int* __restrict__ fidx, int* __restrict__ meta,
                            int* __restrict__ list, int* __restrict__ inv) {
    int i = blockIdx.x * 256 + threadIdx.x;
    if (i < NPAIR) {
        int e = fidx[i];
        int pos = atomicAdd(&meta[32 + e], 1);
        list[pos] = i;
        inv[i] = pos;
    }
}

// ---------------- transpose-convert [E][R][C] fp32 -> [E][C][R] bf16 ----------------
template <int R, int C>
__device__ __forceinline__ void convT_body(const float* __restrict__ src, ushort* __restrict__ dst) {
    int r0 = blockIdx.x * 32, c0 = blockIdx.y * 32;
    __shared__ float tile[32][33];
    int tx = threadIdx.x & 31, ty = threadIdx.x >> 5;  // 256 thr
#pragma unroll
    for (int i = 0; i < 32; i += 8)
        tile[ty + i][tx] = src[(size_t)(r0 + ty + i) * C + c0 + tx];
    __syncthreads();
#pragma unroll
    for (int i = 0; i < 32; i += 8)
        dst[(size_t)(c0 + ty + i) * R + r0 + tx] = f2b(tile[tx][ty + i]);
}
template <int R, int C>
__global__ void convT_kernel(const float* __restrict__ in, ushort* __restrict__ out) {
    int e = blockIdx.z;
    convT_body<R, C>(in + (size_t)e * R * C, out + (size_t)e * C * R);
}
__global__ void convT_kv(const float* __restrict__ kw, const float* __restrict__ vw,
                         ushort* __restrict__ kwt, ushort* __restrict__ vwt) {
    if (blockIdx.z == 0) convT_body<1024, 128>(kw, kwt);
    else                 convT_body<1024, 128>(vw, vwt);
}

// elementwise fp32 -> bf16 (small arrays)
__global__ void conv_kernel(const float* __restrict__ in, ushort* __restrict__ out, int n) {
    int i = blockIdx.x * 256 + threadIdx.x;
    if (i < n) out[i] = f2b(in[i]);
}

// ---------------- kv: split-K (2 splits) MFMA, dense per-split partials ----------------
__global__ __launch_bounds__(256) void kv_mfma(
    const ushort* __restrict__ xnb, const ushort* __restrict__ kwt,
    const ushort* __restrict__ vwt, float* __restrict__ kpart, float* __restrict__ vpart) {
    const ushort* W = blockIdx.z ? vwt : kwt;
    float* outp = blockIdx.z ? vpart : kpart;
    int m0 = blockIdx.x * 64;
    int s = blockIdx.y;
    int kbase = s * 512;
    __shared__ __align__(16) short As[2][64 * BSTR];
    __shared__ __align__(16) short Bs[2][128 * BSTR];
    int tid = threadIdx.x, w = tid >> 6, lane = tid & 63;
    int sr = lane >> 2, sc = (lane & 3) * 8;
    const ushort* ap = xnb + (size_t)(m0 + w * 16 + sr) * D + kbase + sc;
    const ushort* bp0 = W + (size_t)(w * 32 + sr) * D + kbase + sc;
    const ushort* bp1 = bp0 + (size_t)16 * D;
    int wr = (w >> 1) * 32, wc = (w & 1) * 64;
    int m16 = lane & 15, q = lane >> 4;
    f32x4 acc[2][4] = {};
    KLOOP(16, ap, bp0, bp1, 32)
#pragma unroll
    for (int i = 0; i < 2; i++)
#pragma unroll
        for (int r = 0; r < 4; r++) {
            int m = m0 + wr + i * 16 + q * 4 + r;
#pragma unroll
            for (int j = 0; j < 4; j++)
                outp[((size_t)s * NTOK + m) * HD + wc + j * 16 + m16] = acc[i][j][r];
        }
}

__global__ void kv_reduce(const float* __restrict__ kpart, const float* __restrict__ vpart,
                          const float* __restrict__ kb, const float* __restrict__ vb,
                          ushort* __restrict__ kb16, float* __restrict__ vbf) {
    int t = blockIdx.x, h = threadIdx.x;  // 128
    float ka = kb[h], va = vb[h];
#pragma unroll
    for (int s = 0; s < NSPL; s++) {
        ka += kpart[((size_t)s * NTOK + t) * HD + h];
        va += vpart[((size_t)s * NTOK + t) * HD + h];
    }
    kb16[(size_t)t * HD + h] = f2b(ka);
    vbf[(size_t)t * HD + h] = va;
}

// ---------------- q: split-K (2 splits) MFMA, indirect A, dense partials ----------------
__global__ __launch_bounds__(256) void q_mfma(
    const ushort* __restrict__ xnb, const ushort* __restrict__ qwt,
    const int* __restrict__ meta, const int* __restrict__ list, float* __restrict__ qpart) {
    int e = blockIdx.z;
    int o = meta[96 + e], c = meta[97 + e] - o;
    int m0 = blockIdx.x * 64;
    if (m0 >= c) return;
    int s = blockIdx.y;
    int kbase = s * 512;
    __shared__ __align__(16) short As[2][64 * BSTR];
    __shared__ __align__(16) short Bs[2][128 * BSTR];
    int tid = threadIdx.x, w = tid >> 6, lane = tid & 63;
    int sr = lane >> 2, sc = (lane & 3) * 8;
    int ri = o + m0 + w * 16 + sr; if (ri > NPAIR - 1) ri = NPAIR - 1;
    const ushort* ap = xnb + (size_t)(list[ri] >> 1) * D + kbase + sc;
    const ushort* bp0 = qwt + (size_t)e * HD * D + (size_t)(w * 32 + sr) * D + kbase + sc;
    const ushort* bp1 = bp0 + (size_t)16 * D;
    int wr = (w >> 1) * 32, wc = (w & 1) * 64;
    int m16 = lane & 15, q = lane >> 4;
    f32x4 acc[2][4] = {};
    KLOOP(16, ap, bp0, bp1, 32)
#pragma unroll
    for (int i = 0; i < 2; i++)
#pragma unroll
        for (int r = 0; r < 4; r++) {
            int pos = o + m0 + wr + i * 16 + q * 4 + r;
            if (pos < o + c) {
#pragma unroll
                for (int j = 0; j < 4; j++)
                    qpart[((size_t)s * NPAD + pos) * HD + wc + j * 16 + m16] = acc[i][j][r];
            }
        }
}

__global__ void q_reduce(const float* __restrict__ qpart, const float* __restrict__ qb,
                         const int* __restrict__ aidx, const int* __restrict__ list,
                         ushort* __restrict__ Qg) {
    int pos = blockIdx.x, h = threadIdx.x;  // 128
    int e = aidx[list[pos]];
    float a = qb[e * HD + h];
#pragma unroll
    for (int s = 0; s < NSPL; s++) a += qpart[((size_t)s * NPAD + pos) * HD + h];
    Qg[(size_t)pos * HD + h] = f2b(a * QSCALE);
}

// ---------------- rel: MFMA GEMM  R[pos][r] = Qg[pos] . rel[r] ----------------
__global__ __launch_bounds__(256) void rel_mfma(
    const ushort* __restrict__ Qg, const ushort* __restrict__ relb,
    float* __restrict__ R) {
    int m0 = blockIdx.x * 64;
    int n0 = blockIdx.y * 128;
    __shared__ __align__(16) short As[2][64 * BSTR];
    __shared__ __align__(16) short Bs[2][128 * BSTR];
    int tid = threadIdx.x, w = tid >> 6, lane = tid & 63;
    int sr = lane >> 2, sc = (lane & 3) * 8;
    const ushort* ap = Qg + (size_t)(m0 + w * 16 + sr) * HD + sc;
    int r0 = n0 + w * 32 + sr;      if (r0 > RNUM - 1) r0 = RNUM - 1;
    int r1 = n0 + w * 32 + 16 + sr; if (r1 > RNUM - 1) r1 = RNUM - 1;
    const ushort* bp0 = relb + (size_t)r0 * HD + sc;
    const ushort* bp1 = relb + (size_t)r1 * HD + sc;
    int wr = (w >> 1) * 32, wc = (w & 1) * 64;
    int m16 = lane & 15, q = lane >> 4;
    f32x4 acc[2][4] = {};
    KLOOP(4, ap, bp0, bp1, 32)
#pragma unroll
    for (int i = 0; i < 2; i++)
#pragma unroll
        for (int r = 0; r < 4; r++) {
            int pos = m0 + wr + i * 16 + q * 4 + r;
#pragma unroll
            for (int j = 0; j < 4; j++) {
                int n = n0 + wc + j * 16 + m16;
                if (n < RNUM) R[(size_t)pos * RSTRIDE + n] = acc[i][j][r];
            }
        }
}

// ---------------- s: MFMA QK^T + rel bias, fp32 S out (B staged from bf16 kb16) -------
__global__ __launch_bounds__(256) void s_mfma(
    const ushort* __restrict__ Qg, const ushort* __restrict__ kb16,
    const float* __restrict__ R, const int* __restrict__ meta,
    const int* __restrict__ list, float* __restrict__ S) {
    int bin = blockIdx.z;
    int o = meta[32 + bin], c = meta[bin];
    int m0 = blockIdx.x * 64;
    if (m0 >= c) return;
    int b = bin & 3;
    int n0 = blockIdx.y * 128;
    __shared__ __align__(16) short As[2][64 * BSTR];
    __shared__ __align__(16) short Bs[2][128 * BSTR];
    int tid = threadIdx.x, w = tid >> 6, lane = tid & 63;
    int sr = lane >> 2, sc = (lane & 3) * 8;
    int ar = o + m0 + w * 16 + sr; if (ar > NPAIR - 1) ar = NPAIR - 1;   // poison guard
    const ushort* ap = Qg + (size_t)ar * HD + sc;
    const ushort* bp0 = kb16 + ((size_t)b * SEQ + n0 + w * 32 + sr) * HD + sc;
    const ushort* bp1 = bp0 + (size_t)16 * HD;
    int wr = (w >> 1) * 32, wc = (w & 1) * 64;
    int m16 = lane & 15, q = lane >> 4;
    f32x4 acc[2][4] = {};
    KLOOP(4, ap, bp0, bp1, 32)
#pragma unroll
    for (int i = 0; i < 2; i++)
#pragma unroll
        for (int r = 0; r < 4; r++) {
            int pos = o + m0 + wr + i * 16 + q * 4 + r;
            if (pos < o + c) {
                int qpos = (list[pos] >> 1) & (SEQ - 1);
                const float* Rrow = R + (size_t)pos * RSTRIDE;
                float* sr_ = S + (size_t)pos * SEQ;
#pragma unroll
                for (int j = 0; j < 4; j++) {
                    int key = n0 + wc + j * 16 + m16;
                    int rix = key - qpos;
                    rix = (rix < -MAXPOS ? -MAXPOS : (rix > MAXPOS ? MAXPOS : rix)) + MAXPOS;
                    sr_[key] = acc[i][j][r] + Rrow[rix];
                }
            }
        }
}

// ---------------- Row softmax: fp32 S in, bf16 P out (in place, same row slot) ----------------
__global__ __launch_bounds__(256) void softmax_kernel(float* __restrict__ S) {
    int row = blockIdx.x;
    float4* sr = (float4*)(S + (size_t)row * SEQ);
    float4 v = sr[threadIdx.x];
    float m = fmaxf(fmaxf(v.x, v.y), fmaxf(v.z, v.w));
#pragma unroll
    for (int off = 32; off; off >>= 1) m = fmaxf(m, __shfl_down(m, off));
    __shared__ float red0[4], red1[4];
    int wave = threadIdx.x >> 6, lane = threadIdx.x & 63;
    if (lane == 0) red0[wave] = m;
    __syncthreads();
    m = fmaxf(fmaxf(red0[0], red0[1]), fmaxf(red0[2], red0[3]));
    v.x = __expf(v.x - m); v.y = __expf(v.y - m);
    v.z = __expf(v.z - m); v.w = __expf(v.w - m);
    float s = v.x + v.y + v.z + v.w;
#pragma unroll
    for (int off = 32; off; off >>= 1) s += __shfl_down(s, off);
    if (lane == 0) red1[wave] = s;
    __syncthreads();
    float inv = 1.f / (red1[0] + red1[1] + red1[2] + red1[3]);
    // all reads of this row completed before the preceding barrier; safe in-place bf16 write
    ushort* pr = (ushort*)(S + (size_t)row * SEQ);
    ushort4 p4 = { f2b(v.x * inv), f2b(v.y * inv), f2b(v.z * inv), f2b(v.w * inv) };
    *(ushort4*)(pr + threadIdx.x * 4) = p4;
}

// ---------------- pv: split-K (2 splits) MFMA P@V (bf16 P direct), dense partials -----
__global__ __launch_bounds__(256) void pv_mfma(
    const ushort* __restrict__ Pb, const ushort* __restrict__ vt16,
    const int* __restrict__ meta, float* __restrict__ ppart) {
    int bin = blockIdx.z;
    int o = meta[32 + bin], c = meta[bin];
    int m0 = blockIdx.x * 64;
    if (m0 >= c) return;
    int b = bin & 3;
    int s = blockIdx.y;
    int kbase = s * 512;
    __shared__ __align__(16) short As[2][64 * BSTR];
    __shared__ __align__(16) short Bs[2][128 * BSTR];
    int tid = threadIdx.x, w = tid >> 6, lane = tid & 63;
    int sr = lane >> 2, sc = (lane & 3) * 8;
    int ar = o + m0 + w * 16 + sr; if (ar > NPAIR - 1) ar = NPAIR - 1;   // poison guard
    const ushort* ap = Pb + (size_t)ar * PROW + kbase + sc;
    const ushort* bp0 = vt16 + (size_t)b * HD * SEQ + (size_t)(w * 32 + sr) * SEQ + kbase + sc;
    const ushort* bp1 = bp0 + (size_t)16 * SEQ;
    int wr = (w >> 1) * 32, wc = (w & 1) * 64;
    int m16 = lane & 15, q = lane >> 4;
    f32x4 acc[2][4] = {};
    KLOOP(16, ap, bp0, bp1, 32)
#pragma unroll
    for (int i = 0; i < 2; i++)
#pragma unroll
        for (int r = 0; r < 4; r++) {
            int pos = o + m0 + wr + i * 16 + q * 4 + r;
            if (pos < o + c) {
#pragma unroll
                for (int j = 0; j < 4; j++)
                    ppart[((size_t)s * NPAD + pos) * HD + wc + j * 16 + m16] = acc[i][j][r];
            }
        }
}

__global__ void pv_reduce(const float* __restrict__ ppart, const float* __restrict__ aga,
                          const int* __restrict__ list, ushort* __restrict__ ctx16) {
    int pos = blockIdx.x, h = threadIdx.x;  // 128
    float g = aga[list[pos]];
    float a = 0.f;
#pragma unroll
    for (int s = 0; s < NSPL; s++) a += ppart[((size_t)s * NPAD + pos) * HD + h];
    ctx16[(size_t)pos * HD + h] = f2b(a * g);
}

// ---------------- o: MFMA ctx@o_w, dense bf16 per-pair rows ----------------
__global__ __launch_bounds__(256) void o_mfma(
    const ushort* __restrict__ ctx16, const ushort* __restrict__ owt,
    const int* __restrict__ meta, ushort* __restrict__ Ofb) {
    int e = blockIdx.z;
    int o = meta[96 + e], c = meta[97 + e] - o;
    int m0 = blockIdx.x * 64;
    if (m0 >= c) return;
    int n0 = blockIdx.y * 128;
    __shared__ __align__(16) short As[2][64 * BSTR];
    __shared__ __align__(16) short Bs[2][128 * BSTR];
    int tid = threadIdx.x, w = tid >> 6, lane = tid & 63;
    int sr = lane >> 2, sc = (lane & 3) * 8;
    int ar = o + m0 + w * 16 + sr; if (ar > NPAIR - 1) ar = NPAIR - 1;   // poison guard
    const ushort* ap = ctx16 + (size_t)ar * HD + sc;
    const ushort* bp0 = owt + (size_t)e * D * HD + (size_t)(n0 + w * 32 + sr) * HD + sc;
    const ushort* bp1 = bp0 + (size_t)16 * HD;
    int wr = (w >> 1) * 32, wc = (w & 1) * 64;
    int m16 = lane & 15, q = lane >> 4;
    f32x4 acc[2][4] = {};
    KLOOP(4, ap, bp0, bp1, 32)
#pragma unroll
    for (int i = 0; i < 2; i++)
#pragma unroll
        for (int r = 0; r < 4; r++) {
            int pos = o + m0 + wr + i * 16 + q * 4 + r;
            if (pos < o + c) {
#pragma unroll
                for (int j = 0; j < 4; j++)
                    Ofb[(size_t)pos * D + n0 + wc + j * 16 + m16] = f2b(acc[i][j][r]);
            }
        }
}

// ---------------- attn combine ----------------
__global__ void attn_combine(const float* __restrict__ src, const float* __restrict__ ob,
                             const int* __restrict__ aidx, const float* __restrict__ aga,
                             const int* __restrict__ ainv, const ushort* __restrict__ Ofb,
                             float* __restrict__ x1) {
    int t = blockIdx.x, tid = threadIdx.x;
    int e0 = aidx[t * 2], e1 = aidx[t * 2 + 1];
    float g0 = aga[t * 2], g1 = aga[t * 2 + 1];
    int p0 = ainv[t * 2], p1 = ainv[t * 2 + 1];
#pragma unroll
    for (int i = 0; i < 4; i++) {
        int d = tid + i * 256;
        x1[(size_t)t * D + d] = src[(size_t)t * D + d]
                              + g0 * ob[e0 * D + d] + g1 * ob[e1 * D + d]
                              + b2f(Ofb[(size_t)p0 * D + d]) + b2f(Ofb[(size_t)p1 * D + d]);
    }
}

// ---------------- FFN GEMM1: Hb = g*relu(xn2 @ W1 + b1) ----------------
__global__ __launch_bounds__(256) void ffn_mfma1(
    const ushort* __restrict__ xnb2, const ushort* __restrict__ w1t,
    const float* __restrict__ b1, const int* __restrict__ meta,
    const int* __restrict__ list, const float* __restrict__ fga,
    ushort* __restrict__ Hb) {
    int e = blockIdx.z;
    int o = meta[16 + e], c = meta[e];
    int m0 = blockIdx.x * 64;
    if (m0 >= c) return;
    int n0 = blockIdx.y * 128;
    __shared__ __align__(16) short As[2][64 * BSTR];
    __shared__ __align__(16) short Bs[2][128 * BSTR];
    int tid = threadIdx.x, w = tid >> 6, lane = tid & 63;
    int sr = lane >> 2, sc = (lane & 3) * 8;
    int ri = o + m0 + w * 16 + sr; if (ri > NPAIR - 1) ri = NPAIR - 1;
    const ushort* ap = xnb2 + (size_t)(list[ri] >> 1) * D + sc;
    const ushort* bp0 = w1t + ((size_t)e * FH + n0 + w * 32 + sr) * D + sc;
    const ushort* bp1 = bp0 + (size_t)16 * D;
    int wr = (w >> 1) * 32, wc = (w & 1) * 64;
    int m16 = lane & 15, q = lane >> 4;
    f32x4 acc[2][4] = {};
    KLOOP(32, ap, bp0, bp1, 32)
#pragma unroll
    for (int i = 0; i < 2; i++)
#pragma unroll
        for (int r = 0; r < 4; r++) {
            int pos = o + m0 + wr + i * 16 + q * 4 + r;
            if (pos < o + c) {
                float g = fga[list[pos]];
#pragma unroll
                for (int j = 0; j < 4; j++) {
                    int n = n0 + wc + j * 16 + m16;
                    Hb[(size_t)pos * FH + n] = f2b(g * fmaxf(acc[i][j][r] + b1[e * FH + n], 0.f));
                }
            }
        }
}

// ---------------- FFN GEMM2: Of2b[pos] = Hb @ W2 (dense bf16 rows) ----------------
__global__ __launch_bounds__(256) void ffn_mfma2(
    const ushort* __restrict__ Hb, const ushort* __restrict__ w2t,
    const int* __restrict__ meta, ushort* __restrict__ Of2b) {
    int e = blockIdx.z;
    int o = meta[16 + e], c = meta[e];
    int m0 = blockIdx.x * 64;
    if (m0 >= c) return;
    int n0 = blockIdx.y * 128;
    __shared__ __align__(16) short As[2][64 * BSTR];
    __shared__ __align__(16) short Bs[2][128 * BSTR];
    int tid = threadIdx.x, w = tid >> 6, lane = tid & 63;
    int sr = lane >> 2, sc = (lane & 3) * 8;
    int ar = o + m0 + w * 16 + sr; if (ar > NPAIR - 1) ar = NPAIR - 1;   // poison guard
    const ushort* ap = Hb + (size_t)ar * FH + sc;
    const ushort* bp0 = w2t + ((size_t)e * D + n0 + w * 32 + sr) * FH + sc;
    const ushort* bp1 = bp0 + (size_t)16 * FH;
    int wr = (w >> 1) * 32, wc = (w & 1) * 64;
    int m16 = lane & 15, q = lane >> 4;
    f32x4 acc[2][4] = {};
    KLOOP(16, ap, bp0, bp1, 32)
#pragma unroll
    for (int i = 0; i < 2; i++)
#pragma unroll
        for (int r = 0; r < 4; r++) {
            int pos = o + m0 + wr + i * 16 + q * 4 + r;
            if (pos < o + c) {
#pragma unroll
                for (int j = 0; j < 4; j++)
                    Of2b[(size_t)pos * D + n0 + wc + j * 16 + m16] = f2b(acc[i][j][r]);
            }
        }
}

// ---------------- FFN combine ----------------
__global__ void ffn_combine(const float* __restrict__ x1, const float* __restrict__ b2,
                            const int* __restrict__ fidx, const float* __restrict__ fga,
                            const int* __restrict__ finv, const ushort* __restrict__ Of2b,
                            float* __restrict__ out) {
    int t = blockIdx.x, tid = threadIdx.x;
    int e0 = fidx[t * 2], e1 = fidx[t * 2 + 1];
    float g0 = fga[t * 2], g1 = fga[t * 2 + 1];
    int p0 = finv[t * 2], p1 = finv[t * 2 + 1];
#pragma unroll
    for (int i = 0; i < 4; i++) {
        int d = tid + i * 256;
        out[(size_t)t * D + d] = x1[(size_t)t * D + d]
                               + g0 * b2[e0 * D + d] + g1 * b2[e1 * D + d]
                               + b2f(Of2b[(size_t)p0 * D + d]) + b2f(Of2b[(size_t)p1 * D + d]);
    }
}

extern "C" void kernel_launch(void* const* d_in, const int* in_sizes, int n_in,
                              void* d_out, int out_size, void* d_ws, size_t ws_size,
                              hipStream_t stream) {
    const float* src   = (const float*)d_in[0];
    const float* ln1_w = (const float*)d_in[1];
    const float* ln1_b = (const float*)d_in[2];
    const float* ln2_w = (const float*)d_in[3];
    const float* ln2_b = (const float*)d_in[4];
    const float* agw   = (const float*)d_in[5];
    const float* qw    = (const float*)d_in[6];
    const float* qb    = (const float*)d_in[7];
    const float* kw    = (const float*)d_in[8];
    const float* kb    = (const float*)d_in[9];
    const float* vw    = (const float*)d_in[10];
    const float* vb    = (const float*)d_in[11];
    const float* ow    = (const float*)d_in[12];
    const float* ob    = (const float*)d_in[13];
    const float* rel   = (const float*)d_in[14];
    const float* fgw   = (const float*)d_in[15];
    const float* w1    = (const float*)d_in[16];
    const float* b1    = (const float*)d_in[17];
    const float* w2    = (const float*)d_in[18];
    const float* b2    = (const float*)d_in[19];
    float* out = (float*)d_out;

    char* p = (char*)d_ws;
    float* xn1  = (float*)p; p += (size_t)NTOK * D * 4;               // LN out fp32 (router)
    float* x1   = (float*)p; p += (size_t)NTOK * D * 4;
    char*  sreg = p;         p += (size_t)NPAD * SEQ * 4;             // 34.1 MB
    float*  Sbuf = (float*)sreg;                                      // attn: scores (fp32) / P (bf16 in place)
    ushort* Pb   = (ushort*)sreg;                                     // bf16 P, row stride PROW
    ushort* Ofb  = (ushort*)sreg;                                     // attn: o rows (17 MB)
    ushort* w1t  = (ushort*)sreg;                                     // FFN: 16.78 MB
    ushort* w2t  = (ushort*)(sreg + (size_t)16777216);                // FFN: 16.78 MB
    char*  reg  = p;         p += (size_t)NPAD * 128 * 6 + (size_t)NPAIR * RSTRIDE * 4;
    ushort* ctx16 = (ushort*)reg;                                     // bf16 ctx (2.13 MB slot)
    ushort* Qg   = (ushort*)(reg + (size_t)NPAD * 128 * 4);           // 2.13 MB
    float*  Rbuf = (float*)(reg + (size_t)NPAD * 128 * 6);            // 4.33 MB
    ushort* Hb   = (ushort*)reg;                                      // FFN hidden (8.52 MB)
    char*  arena = p;        p += (size_t)4 * NPAD * 128 * 4;         // 17.04 MB
    float*  kpart = (float*)arena;
    float*  vpart = (float*)(arena + (size_t)NSPL * NTOK * HD * 4);
    float*  qpart = (float*)arena;
    float*  ppart = (float*)arena;
    ushort* Of2b  = (ushort*)arena;
    ushort* kb16 = (ushort*)p; p += (size_t)NTOK * HD * 2;
    float* vbf  = (float*)p; p += (size_t)NTOK * HD * 4;
    ushort* vt16 = (ushort*)p; p += (size_t)NTOK * HD * 2;
    ushort* kwt = (ushort*)p; p += (size_t)HD * D * 2;
    ushort* vwt = (ushort*)p; p += (size_t)HD * D * 2;
    ushort* qwt = (ushort*)p; p += (size_t)EA * HD * D * 2;
    ushort* owt = (ushort*)p; p += (size_t)EA * D * HD * 2;
    ushort* relb = (ushort*)p; p += (size_t)RNUM * HD * 2 + 256;
    int*   aidx = (int*)p;   p += NPAIR * 4;
    float* aga  = (float*)p; p += NPAIR * 4;
    int*   fidx = (int*)p;   p += NPAIR * 4;
    float* fga  = (float*)p; p += NPAIR * 4;
    int*   ameta = (int*)p;  p += 128 * 4;
    int*   alist = (int*)p;  p += NPAIR * 4;
    int*   ainv = (int*)p;   p += NPAIR * 4;
    int*   fmeta = (int*)p;  p += 64 * 4;
    int*   flist = (int*)p;  p += NPAIR * 4;
    int*   finv = (int*)p;   p += NPAIR * 4;
    ushort* xnb = (ushort*)p; p += (size_t)NTOK * D * 2;              // bf16 LN out (GEMM A operand)
    float* xn2 = xn1;

    // ---- attention ----
    zero_meta<<<1, 128, 0, stream>>>(ameta, fmeta);
    ln_kernel<<<NTOK, 256, 0, stream>>>(src, ln1_w, ln1_b, xn1, xnb);
    router_kernel<EA><<<NTOK, 64, 0, stream>>>(xn1, agw, aidx, aga);
    abin_count<<<NPAIR / 256, 256, 0, stream>>>(aidx, ameta);
    abin_scan<<<1, 64, 0, stream>>>(ameta);
    abin_scatter<<<NPAIR / 256, 256, 0, stream>>>(aidx, ameta, alist, ainv);
    convT_kv<<<dim3(32, 4, 2), 256, 0, stream>>>(kw, vw, kwt, vwt);
    convT_kernel<1024, 128><<<dim3(32, 4, EA), 256, 0, stream>>>(qw, qwt);
    convT_kernel<128, 1024><<<dim3(4, 32, EA), 256, 0, stream>>>(ow, owt);
    conv_kernel<<<(RNUM * HD + 255) / 256, 256, 0, stream>>>(rel, relb, RNUM * HD);
    kv_mfma<<<dim3(64, NSPL, 2), 256, 0, stream>>>(xnb, kwt, vwt, kpart, vpart);
    kv_reduce<<<NTOK, 128, 0, stream>>>(kpart, vpart, kb, vb, kb16, vbf);
    convT_kernel<1024, 128><<<dim3(32, 4, 4), 256, 0, stream>>>(vbf, vt16);
    q_mfma<<<dim3(40, NSPL, EA), 256, 0, stream>>>(xnb, qwt, ameta, alist, qpart);
    q_reduce<<<NPAIR, 128, 0, stream>>>(qpart, qb, aidx, alist, Qg);
    rel_mfma<<<dim3(NPAIR / 64, 2), 256, 0, stream>>>(Qg, relb, Rbuf);
    s_mfma<<<dim3(12, 8, 32), 256, 0, stream>>>(Qg, kb16, Rbuf, ameta, alist, Sbuf);
    softmax_kernel<<<NPAIR, 256, 0, stream>>>(Sbuf);
    pv_mfma<<<dim3(12, NSPL, 32), 256, 0, stream>>>(Pb, vt16, ameta, ppart);
    pv_reduce<<<NPAIR, 128, 0, stream>>>(ppart, aga, alist, ctx16);
    o_mfma<<<dim3(40, 8, EA), 256, 0, stream>>>(ctx16, owt, ameta, Ofb);
    attn_combine<<<NTOK, 256, 0, stream>>>(src, ob, aidx, aga, ainv, Ofb, x1);

    // ---- FFN ----
    ln_kernel<<<NTOK, 256, 0, stream>>>(x1, ln2_w, ln2_b, xn2, xnb);
    router_kernel<EF><<<NTOK, 64, 0, stream>>>(xn2, fgw, fidx, fga);
    bin_count<<<NPAIR / 256, 256, 0, stream>>>(fidx, fmeta);
    bin_scan<<<1, 64, 0, stream>>>(fmeta);
    bin_scatter<<<NPAIR / 256, 256, 0, stream>>>(fidx, fmeta, flist, finv);
    convT_kernel<1024, 512><<<dim3(32, 16, EF), 256, 0, stream>>>(w1, w1t);
    convT_kernel<512, 1024><<<dim3(16, 32, EF), 256, 0, stream>>>(w2, w2t);
    ffn_mfma1<<<dim3(20, 4, EF), 256, 0, stream>>>(xnb, w1t, b1, fmeta, flist, fga, Hb);
    ffn_mfma2<<<dim3(20, 8, EF), 256, 0, stream>>>(Hb, w2t, fmeta, Of2b);
    ffn_combine<<<NTOK, 256, 0, stream>>>(x1, b2, fidx, fga, finv, Of2b, out);
}